// Round 1
// baseline (4554.799 us; speedup 1.0000x reference)
//
#include <hip/hip_runtime.h>
#include <math.h>

#define NEG_SLOPE 0.2f
#define BN_EPS 1e-5f

// ---------- helpers ----------

__device__ __forceinline__ void atomAddF(float* p, float v) {
#if defined(__HIP_PLATFORM_AMD__)
    unsafeAtomicAdd(p, v);   // native global_atomic_add_f32 on gfx90a+
#else
    atomicAdd(p, v);
#endif
}

// monotone float<->uint mapping for atomicMax on floats
__device__ __forceinline__ unsigned flipf(float f) {
    unsigned u = __float_as_uint(f);
    return (u & 0x80000000u) ? ~u : (u | 0x80000000u);
}
__device__ __forceinline__ float unflipf(unsigned u) {
    return (u & 0x80000000u) ? __uint_as_float(u & 0x7fffffffu) : __uint_as_float(~u);
}

__device__ __forceinline__ void edge_sd(const int* __restrict__ ei, int E, int eid, int& s, int& d) {
    if (eid < E) { s = ei[eid]; d = ei[E + eid]; }
    else         { s = d = eid - E; }   // self-loops appended after the E real edges
}

__device__ __forceinline__ float lrelu(float v) { return v > 0.f ? v : NEG_SLOPE * v; }

// ---------- GEMM: Y[N,128] = X[N,128] @ W[128,128] ----------
// 64-row x 128-col tile per 256-thread block; X tile in LDS, W streamed (L2).
__global__ __launch_bounds__(256) void gemm128(const float* __restrict__ X,
                                               const float* __restrict__ W,
                                               float* __restrict__ Y, int Nrows) {
    __shared__ float xs[64 * 128];
    int bm = blockIdx.x * 64;
    int tid = threadIdx.x;

    const float4* Xv = (const float4*)(X + (size_t)bm * 128);
    float4* xsv = (float4*)xs;
    for (int i = tid; i < 64 * 32; i += 256) {
        int row = i >> 5;
        xsv[i] = (bm + row < Nrows) ? Xv[i] : make_float4(0.f, 0.f, 0.f, 0.f);
    }
    __syncthreads();

    int cq = tid & 31;   // column quad: cols cq*4..cq*4+3
    int rg = tid >> 5;   // row group: rows rg*8..rg*8+7

    float acc[8][4];
#pragma unroll
    for (int r = 0; r < 8; r++)
#pragma unroll
        for (int j = 0; j < 4; j++) acc[r][j] = 0.f;

    const float* xbase = xs + (rg * 8) * 128;
#pragma unroll 4
    for (int k = 0; k < 128; k++) {
        float4 w4 = *(const float4*)(W + k * 128 + cq * 4);
#pragma unroll
        for (int r = 0; r < 8; r++) {
            float xv = xbase[r * 128 + k];
            acc[r][0] += xv * w4.x;
            acc[r][1] += xv * w4.y;
            acc[r][2] += xv * w4.z;
            acc[r][3] += xv * w4.w;
        }
    }
#pragma unroll
    for (int r = 0; r < 8; r++) {
        int row = bm + rg * 8 + r;
        if (row < Nrows)
            *(float4*)(Y + (size_t)row * 128 + cq * 4) =
                make_float4(acc[r][0], acc[r][1], acc[r][2], acc[r][3]);
    }
}

// ---------- attention logits per node: a_src[n,h], a_dst[n,h] ----------
__global__ void att_kernel(const float* __restrict__ Hm,
                           const float* __restrict__ att_s,
                           const float* __restrict__ att_d,
                           float* __restrict__ a_src, float* __restrict__ a_dst, int N) {
    int idx = blockIdx.x * 256 + threadIdx.x;   // n*8 + h
    if (idx >= N * 8) return;
    int n = idx >> 3, h = idx & 7;
    const float* hp = Hm + (size_t)n * 128 + h * 16;
    float ss = 0.f, sd = 0.f;
#pragma unroll
    for (int c = 0; c < 16; c++) {
        float v = hp[c];
        ss += v * att_s[h * 16 + c];
        sd += v * att_d[h * 16 + c];
    }
    a_src[idx] = ss;
    a_dst[idx] = sd;
}

// ---------- edge pass 1: segment max (flipped-uint atomicMax) ----------
__global__ void edge_max_kernel(const int* __restrict__ ei, int E, int Etot,
                                const float* __restrict__ a_src, const float* __restrict__ a_dst,
                                unsigned* __restrict__ m) {
    int eid = blockIdx.x * 256 + threadIdx.x;
    if (eid >= Etot) return;
    int s, d;
    edge_sd(ei, E, eid, s, d);
    float4 s0 = *(const float4*)(a_src + s * 8);
    float4 s1 = *(const float4*)(a_src + s * 8 + 4);
    float4 d0 = *(const float4*)(a_dst + d * 8);
    float4 d1 = *(const float4*)(a_dst + d * 8 + 4);
    float e[8] = {s0.x + d0.x, s0.y + d0.y, s0.z + d0.z, s0.w + d0.w,
                  s1.x + d1.x, s1.y + d1.y, s1.z + d1.z, s1.w + d1.w};
    unsigned* mp = m + d * 8;
#pragma unroll
    for (int h = 0; h < 8; h++) atomicMax(&mp[h], flipf(lrelu(e[h])));
}

// ---------- edge pass 2: segment sum of exp(e - m[dst]) ----------
__global__ void edge_sum_kernel(const int* __restrict__ ei, int E, int Etot,
                                const float* __restrict__ a_src, const float* __restrict__ a_dst,
                                const unsigned* __restrict__ m, float* __restrict__ denom) {
    int eid = blockIdx.x * 256 + threadIdx.x;
    if (eid >= Etot) return;
    int s, d;
    edge_sd(ei, E, eid, s, d);
    float4 s0 = *(const float4*)(a_src + s * 8);
    float4 s1 = *(const float4*)(a_src + s * 8 + 4);
    float4 d0 = *(const float4*)(a_dst + d * 8);
    float4 d1 = *(const float4*)(a_dst + d * 8 + 4);
    float e[8] = {s0.x + d0.x, s0.y + d0.y, s0.z + d0.z, s0.w + d0.w,
                  s1.x + d1.x, s1.y + d1.y, s1.z + d1.z, s1.w + d1.w};
    float* dp = denom + d * 8;
    const unsigned* mp = m + d * 8;
#pragma unroll
    for (int h = 0; h < 8; h++) {
        float ex = __expf(lrelu(e[h]) - unflipf(mp[h]));
        atomAddF(&dp[h], ex);
    }
}

// ---------- edge pass 3: out[dst] += h[src] * alpha  (32 threads / edge) ----------
__global__ void edge_agg_kernel(const int* __restrict__ ei, int E, int Etot,
                                const float* __restrict__ Hfeat,
                                const float* __restrict__ a_src, const float* __restrict__ a_dst,
                                const unsigned* __restrict__ m, const float* __restrict__ denom,
                                float* __restrict__ out) {
    long gid = (long)blockIdx.x * 256 + threadIdx.x;
    int eid = (int)(gid >> 5);
    if (eid >= Etot) return;
    int lane = (int)(gid & 31);   // cols lane*4..+3; head = lane>>2
    int s, d;
    edge_sd(ei, E, eid, s, d);
    int h = lane >> 2;
    float e = lrelu(a_src[s * 8 + h] + a_dst[d * 8 + h]);
    float mu = unflipf(m[d * 8 + h]);
    float den = denom[d * 8 + h];
    float alpha = __expf(e - mu) / (den + 1e-16f);
    float4 hv = *(const float4*)(Hfeat + (size_t)s * 128 + lane * 4);
    float* op = out + (size_t)d * 128 + lane * 4;
    atomAddF(op + 0, hv.x * alpha);
    atomAddF(op + 1, hv.y * alpha);
    atomAddF(op + 2, hv.z * alpha);
    atomAddF(op + 3, hv.w * alpha);
}

// ---------- batch-norm stats: per-column sum & sumsq ----------
__global__ void stats_kernel(const float* __restrict__ X, int Nrows, int C,
                             float* __restrict__ sums, float* __restrict__ sumsq,
                             int rows_per_block) {
    int c = threadIdx.x % C;
    int g = threadIdx.x / C;
    int gsz = 256 / C;
    long base = (long)blockIdx.x * rows_per_block;
    float s = 0.f, q = 0.f;
    for (int r = g; r < rows_per_block; r += gsz) {
        long row = base + r;
        if (row < Nrows) {
            float v = X[row * C + c];
            s += v;
            q += v * v;
        }
    }
    atomAddF(&sums[c], s);
    atomAddF(&sumsq[c], q);
}

__global__ void finalize_stats(const float* __restrict__ sums, const float* __restrict__ sumsq,
                               float* __restrict__ mu, float* __restrict__ rsig,
                               int C, float invN) {
    int c = threadIdx.x;
    if (c >= C) return;
    float m_ = sums[c] * invN;
    float v = sumsq[c] * invN - m_ * m_;
    mu[c] = m_;
    rsig[c] = rsqrtf(v + BN_EPS);
}

// ---------- BN + ELU elementwise (128 cols, float4) ----------
__global__ void bn_elu_kernel(const float* __restrict__ X,
                              const float* __restrict__ mu, const float* __restrict__ rsig,
                              const float* __restrict__ gamma, const float* __restrict__ beta,
                              float* __restrict__ Y, long total4) {
    long i = (long)blockIdx.x * 256 + threadIdx.x;
    if (i >= total4) return;
    int c4 = (int)(i & 31) * 4;
    float4 x = ((const float4*)X)[i];
    float r[4] = {x.x, x.y, x.z, x.w};
#pragma unroll
    for (int j = 0; j < 4; j++) {
        int c = c4 + j;
        float v = (r[j] - mu[c]) * rsig[c] * gamma[c] + beta[c];
        r[j] = v > 0.f ? v : (__expf(v) - 1.f);   // ELU
    }
    ((float4*)Y)[i] = make_float4(r[0], r[1], r[2], r[3]);
}

// ---------- mean over heads: [N,8,16] -> [N,16] ----------
__global__ void headmean_kernel(const float* __restrict__ X, float* __restrict__ out1, int N) {
    int idx = blockIdx.x * 256 + threadIdx.x;   // n*4 + c4
    if (idx >= N * 4) return;
    int n = idx >> 2, c4 = (idx & 3) * 4;
    float4 acc = make_float4(0.f, 0.f, 0.f, 0.f);
#pragma unroll
    for (int h = 0; h < 8; h++) {
        float4 v = *(const float4*)(X + (size_t)n * 128 + h * 16 + c4);
        acc.x += v.x; acc.y += v.y; acc.z += v.z; acc.w += v.w;
    }
    acc.x *= 0.125f; acc.y *= 0.125f; acc.z *= 0.125f; acc.w *= 0.125f;
    *(float4*)(out1 + (size_t)n * 16 + c4) = acc;
}

// ---------- final: BN(16) + logits = v @ Wc + bc ----------
__global__ void final_kernel(const float* __restrict__ out1,
                             const float* __restrict__ mu, const float* __restrict__ rsig,
                             const float* __restrict__ gamma, const float* __restrict__ beta,
                             const float* __restrict__ Wc, const float* __restrict__ bc,
                             float* __restrict__ out, int N) {
    int n = blockIdx.x * 256 + threadIdx.x;
    if (n >= N) return;
    float l0 = bc[0], l1 = bc[1];
#pragma unroll
    for (int c = 0; c < 16; c++) {
        float v = (out1[(size_t)n * 16 + c] - mu[c]) * rsig[c] * gamma[c] + beta[c];
        l0 += v * Wc[c * 2 + 0];
        l1 += v * Wc[c * 2 + 1];
    }
    out[(size_t)n * 2 + 0] = l0;
    out[(size_t)n * 2 + 1] = l1;
}

// ---------- launcher ----------
extern "C" void kernel_launch(void* const* d_in, const int* in_sizes, int n_in,
                              void* d_out, int out_size, void* d_ws, size_t ws_size,
                              hipStream_t stream) {
    const float* x   = (const float*)d_in[0];
    const int*   ei  = (const int*)d_in[1];
    const float* W0  = (const float*)d_in[2];
    const float* as0 = (const float*)d_in[3];
    const float* ad0 = (const float*)d_in[4];
    // d_in[5] = b0: cancelled exactly by the following batch-norm's mean subtraction
    const float* g0  = (const float*)d_in[6];
    const float* be0 = (const float*)d_in[7];
    const float* W1  = (const float*)d_in[8];
    const float* as1 = (const float*)d_in[9];
    const float* ad1 = (const float*)d_in[10];
    // d_in[11] = b1: cancelled by BN as well
    const float* g1  = (const float*)d_in[12];
    const float* be1 = (const float*)d_in[13];
    const float* Wc  = (const float*)d_in[14];
    const float* bc  = (const float*)d_in[15];
    float* out = (float*)d_out;

    int N = in_sizes[0] / 128;
    int E = in_sizes[1] / 2;
    int Etot = E + N;

    // workspace layout
    char* ws = (char*)d_ws;
    size_t off = 0;
    auto walloc = [&](size_t bytes) -> void* {
        void* p = ws + off;
        off += (bytes + 255) & ~(size_t)255;
        return p;
    };
    float*    A     = (float*)walloc((size_t)N * 128 * 4);
    float*    B     = (float*)walloc((size_t)N * 128 * 4);
    float*    a_src = (float*)walloc((size_t)N * 8 * 4);
    float*    a_dst = (float*)walloc((size_t)N * 8 * 4);
    unsigned* m     = (unsigned*)walloc((size_t)N * 8 * 4);
    float*    denom = (float*)walloc((size_t)N * 8 * 4);
    float*    out1  = (float*)walloc((size_t)N * 16 * 4);
    float*    stats = (float*)walloc(4 * 128 * 4);
    float* sums = stats, * sumsq = stats + 128, * mu = stats + 256, * rsig = stats + 384;

    dim3 b256(256);
    int gN64   = (N + 63) / 64;
    int gNH    = (N * 8 + 255) / 256;
    int gE     = (Etot + 255) / 256;
    int gEagg  = (int)(((long)Etot * 32 + 255) / 256);
    int gElem4 = (int)(((long)N * 32 + 255) / 256);
    int gStats = (N + 127) / 128;

    auto run_edges = [&](const float* Hbuf, float* Aggbuf) {
        hipMemsetAsync(m, 0, (size_t)N * 8 * 4, stream);
        hipMemsetAsync(denom, 0, (size_t)N * 8 * 4, stream);
        hipMemsetAsync(Aggbuf, 0, (size_t)N * 128 * 4, stream);
        edge_max_kernel<<<gE, b256, 0, stream>>>(ei, E, Etot, a_src, a_dst, m);
        edge_sum_kernel<<<gE, b256, 0, stream>>>(ei, E, Etot, a_src, a_dst, m, denom);
        edge_agg_kernel<<<gEagg, b256, 0, stream>>>(ei, E, Etot, Hbuf, a_src, a_dst, m, denom, Aggbuf);
    };

    // ---- layer 0 ----
    gemm128<<<gN64, b256, 0, stream>>>(x, W0, A, N);                  // A = h0
    att_kernel<<<gNH, b256, 0, stream>>>(A, as0, ad0, a_src, a_dst, N);
    run_edges(A, B);                                                   // B = agg0
    hipMemsetAsync(sums, 0, 2 * 128 * 4, stream);
    stats_kernel<<<gStats, b256, 0, stream>>>(B, N, 128, sums, sumsq, 128);
    finalize_stats<<<1, 128, 0, stream>>>(sums, sumsq, mu, rsig, 128, 1.0f / N);
    bn_elu_kernel<<<gElem4, b256, 0, stream>>>(B, mu, rsig, g0, be0, A, (long)N * 32); // A = h1_in

    // ---- layer 1 ----
    gemm128<<<gN64, b256, 0, stream>>>(A, W1, B, N);                  // B = h1
    att_kernel<<<gNH, b256, 0, stream>>>(B, as1, ad1, a_src, a_dst, N);
    run_edges(B, A);                                                   // A = agg1
    headmean_kernel<<<(N * 4 + 255) / 256, b256, 0, stream>>>(A, out1, N);
    hipMemsetAsync(sums, 0, 2 * 128 * 4, stream);
    stats_kernel<<<gStats, b256, 0, stream>>>(out1, N, 16, sums, sumsq, 128);
    finalize_stats<<<1, 16, 0, stream>>>(sums, sumsq, mu, rsig, 16, 1.0f / N);
    final_kernel<<<(N + 255) / 256, b256, 0, stream>>>(out1, mu, rsig, g1, be1, Wc, bc, out, N);
}

// Round 2
// 873.365 us; speedup vs baseline: 5.2152x; 5.2152x over previous
//
#include <hip/hip_runtime.h>
#include <math.h>

#define NEG_SLOPE 0.2f
#define BN_EPS 1e-5f

// ---------- helpers ----------

__device__ __forceinline__ void atomAddF(float* p, float v) {
#if defined(__HIP_PLATFORM_AMD__)
    unsafeAtomicAdd(p, v);   // native global_atomic_add_f32 on gfx90a+
#else
    atomicAdd(p, v);
#endif
}

__device__ __forceinline__ void edge_sd(const int* __restrict__ ei, int E, int eid, int& s, int& d) {
    if (eid < E) { s = ei[eid]; d = ei[E + eid]; }
    else         { s = d = eid - E; }   // self-loops appended after the E real edges
}

__device__ __forceinline__ float lrelu(float v) { return v > 0.f ? v : NEG_SLOPE * v; }

// ---------- GEMM: Y[N,128] = X[N,128] @ W[128,128] ----------
__global__ __launch_bounds__(256) void gemm128(const float* __restrict__ X,
                                               const float* __restrict__ W,
                                               float* __restrict__ Y, int Nrows) {
    __shared__ float xs[64 * 128];
    int bm = blockIdx.x * 64;
    int tid = threadIdx.x;

    const float4* Xv = (const float4*)(X + (size_t)bm * 128);
    float4* xsv = (float4*)xs;
    for (int i = tid; i < 64 * 32; i += 256) {
        int row = i >> 5;
        xsv[i] = (bm + row < Nrows) ? Xv[i] : make_float4(0.f, 0.f, 0.f, 0.f);
    }
    __syncthreads();

    int cq = tid & 31;   // column quad: cols cq*4..cq*4+3
    int rg = tid >> 5;   // row group: rows rg*8..rg*8+7

    float acc[8][4];
#pragma unroll
    for (int r = 0; r < 8; r++)
#pragma unroll
        for (int j = 0; j < 4; j++) acc[r][j] = 0.f;

    const float* xbase = xs + (rg * 8) * 128;
#pragma unroll 4
    for (int k = 0; k < 128; k++) {
        float4 w4 = *(const float4*)(W + k * 128 + cq * 4);
#pragma unroll
        for (int r = 0; r < 8; r++) {
            float xv = xbase[r * 128 + k];
            acc[r][0] += xv * w4.x;
            acc[r][1] += xv * w4.y;
            acc[r][2] += xv * w4.z;
            acc[r][3] += xv * w4.w;
        }
    }
#pragma unroll
    for (int r = 0; r < 8; r++) {
        int row = bm + rg * 8 + r;
        if (row < Nrows)
            *(float4*)(Y + (size_t)row * 128 + cq * 4) =
                make_float4(acc[r][0], acc[r][1], acc[r][2], acc[r][3]);
    }
}

// ---------- attention logits per node: a_src[n,h], a_dst[n,h] ----------
__global__ void att_kernel(const float* __restrict__ Hm,
                           const float* __restrict__ att_s,
                           const float* __restrict__ att_d,
                           float* __restrict__ a_src, float* __restrict__ a_dst, int N) {
    int idx = blockIdx.x * 256 + threadIdx.x;   // n*8 + h
    if (idx >= N * 8) return;
    int n = idx >> 3, h = idx & 7;
    const float* hp = Hm + (size_t)n * 128 + h * 16;
    float ss = 0.f, sd = 0.f;
#pragma unroll
    for (int c = 0; c < 16; c++) {
        float v = hp[c];
        ss += v * att_s[h * 16 + c];
        sd += v * att_d[h * 16 + c];
    }
    a_src[idx] = ss;
    a_dst[idx] = sd;
}

// ---------- CSR build: histogram of dst ----------
__global__ void hist_kernel(const int* __restrict__ ei, int E, int Etot,
                            int* __restrict__ counts) {
    int eid = blockIdx.x * 256 + threadIdx.x;
    if (eid >= Etot) return;
    int s, d;
    edge_sd(ei, E, eid, s, d);
    atomicAdd(&counts[d], 1);
}

// ---------- CSR build: single-block exclusive scan over counts -> rowptr ----------
__global__ __launch_bounds__(1024) void scan_kernel(const int* __restrict__ counts,
                                                    int* __restrict__ rowptr, int N) {
    __shared__ int wsum[16];
    __shared__ int carry;
    int tid = threadIdx.x, lane = tid & 63, wid = tid >> 6;
    if (tid == 0) { carry = 0; rowptr[0] = 0; }
    __syncthreads();
    for (int base = 0; base < N; base += 1024) {
        int idx = base + tid;
        int incl = (idx < N) ? counts[idx] : 0;
#pragma unroll
        for (int off = 1; off < 64; off <<= 1) {
            int t = __shfl_up(incl, off);
            if (lane >= off) incl += t;
        }
        if (lane == 63) wsum[wid] = incl;
        __syncthreads();
        int woff = 0;
        for (int w = 0; w < wid; w++) woff += wsum[w];
        int c = carry;
        if (idx < N) rowptr[idx + 1] = c + woff + incl;
        __syncthreads();
        if (tid == 0) {
            int t = 0;
            for (int w = 0; w < 16; w++) t += wsum[w];
            carry = c + t;
        }
        __syncthreads();
    }
}

// ---------- CSR build: scatter src ids into dst-sorted order ----------
__global__ void scatter_kernel(const int* __restrict__ ei, int E, int Etot,
                               const int* __restrict__ rowptr, int* __restrict__ fill,
                               int* __restrict__ ssrc) {
    int eid = blockIdx.x * 256 + threadIdx.x;
    if (eid >= Etot) return;
    int s, d;
    edge_sd(ei, E, eid, s, d);
    int pos = rowptr[d] + atomicAdd(&fill[d], 1);
    ssrc[pos] = s;
}

// ---------- fused softmax + aggregation: one wave per destination node ----------
// lanes 0..63: head h = lane>>3 (8 lanes/head) for softmax phase;
// features f = 2*lane, 2*lane+1 (head f/16 == lane>>3, consistent) for agg phase.
__global__ __launch_bounds__(256) void agg_kernel(const int* __restrict__ rowptr,
                                                  const int* __restrict__ ssrc,
                                                  const float* __restrict__ a_src,
                                                  const float* __restrict__ a_dst,
                                                  const float* __restrict__ Hfeat,
                                                  float* __restrict__ outbuf, int N) {
    int wid = threadIdx.x >> 6;
    int dst = blockIdx.x * 4 + wid;
    if (dst >= N) return;
    int lane = threadIdx.x & 63;
    int h = lane >> 3;
    int start = rowptr[dst], end = rowptr[dst + 1];
    float adst = a_dst[dst * 8 + h];

    // phase 1: online softmax (max + sum of exp), 8 lanes per head, stride 8
    float mloc = -1e30f, sloc = 0.f;
    for (int i = start + (lane & 7); i < end; i += 8) {
        int s = ssrc[i];
        float e = lrelu(a_src[s * 8 + h] + adst);
        float nm = fmaxf(mloc, e);
        sloc = sloc * __expf(mloc - nm) + __expf(e - nm);
        mloc = nm;
    }
#pragma unroll
    for (int off = 1; off < 8; off <<= 1) {
        float om = __shfl_xor(mloc, off);
        float os = __shfl_xor(sloc, off);
        float nm = fmaxf(mloc, om);
        sloc = sloc * __expf(mloc - nm) + os * __expf(om - nm);
        mloc = nm;
    }
    float inv = 1.f / (sloc + 1e-16f);

    // phase 2: weighted feature accumulation, all 64 lanes per edge (float2 each)
    float acc0 = 0.f, acc1 = 0.f;
    int f = lane * 2;
    for (int i = start; i < end; i++) {
        int s = ssrc[i];
        float e = lrelu(a_src[s * 8 + h] + adst);
        float alpha = __expf(e - mloc) * inv;
        float2 hv = *(const float2*)(Hfeat + (size_t)s * 128 + f);
        acc0 += hv.x * alpha;
        acc1 += hv.y * alpha;
    }
    *(float2*)(outbuf + (size_t)dst * 128 + f) = make_float2(acc0, acc1);
}

// ---------- batch-norm stats: per-column sum & sumsq ----------
__global__ void stats_kernel(const float* __restrict__ X, int Nrows, int C,
                             float* __restrict__ sums, float* __restrict__ sumsq,
                             int rows_per_block) {
    int c = threadIdx.x % C;
    int g = threadIdx.x / C;
    int gsz = 256 / C;
    long base = (long)blockIdx.x * rows_per_block;
    float s = 0.f, q = 0.f;
    for (int r = g; r < rows_per_block; r += gsz) {
        long row = base + r;
        if (row < Nrows) {
            float v = X[row * C + c];
            s += v;
            q += v * v;
        }
    }
    atomAddF(&sums[c], s);
    atomAddF(&sumsq[c], q);
}

__global__ void finalize_stats(const float* __restrict__ sums, const float* __restrict__ sumsq,
                               float* __restrict__ mu, float* __restrict__ rsig,
                               int C, float invN) {
    int c = threadIdx.x;
    if (c >= C) return;
    float m_ = sums[c] * invN;
    float v = sumsq[c] * invN - m_ * m_;
    mu[c] = m_;
    rsig[c] = rsqrtf(v + BN_EPS);
}

// ---------- BN + ELU elementwise (128 cols, float4) ----------
__global__ void bn_elu_kernel(const float* __restrict__ X,
                              const float* __restrict__ mu, const float* __restrict__ rsig,
                              const float* __restrict__ gamma, const float* __restrict__ beta,
                              float* __restrict__ Y, long total4) {
    long i = (long)blockIdx.x * 256 + threadIdx.x;
    if (i >= total4) return;
    int c4 = (int)(i & 31) * 4;
    float4 x = ((const float4*)X)[i];
    float r[4] = {x.x, x.y, x.z, x.w};
#pragma unroll
    for (int j = 0; j < 4; j++) {
        int c = c4 + j;
        float v = (r[j] - mu[c]) * rsig[c] * gamma[c] + beta[c];
        r[j] = v > 0.f ? v : expm1f(v);   // ELU
    }
    ((float4*)Y)[i] = make_float4(r[0], r[1], r[2], r[3]);
}

// ---------- mean over heads: [N,8,16] -> [N,16] ----------
__global__ void headmean_kernel(const float* __restrict__ X, float* __restrict__ out1, int N) {
    int idx = blockIdx.x * 256 + threadIdx.x;   // n*4 + c4
    if (idx >= N * 4) return;
    int n = idx >> 2, c4 = (idx & 3) * 4;
    float4 acc = make_float4(0.f, 0.f, 0.f, 0.f);
#pragma unroll
    for (int h = 0; h < 8; h++) {
        float4 v = *(const float4*)(X + (size_t)n * 128 + h * 16 + c4);
        acc.x += v.x; acc.y += v.y; acc.z += v.z; acc.w += v.w;
    }
    acc.x *= 0.125f; acc.y *= 0.125f; acc.z *= 0.125f; acc.w *= 0.125f;
    *(float4*)(out1 + (size_t)n * 16 + c4) = acc;
}

// ---------- final: BN(16) + logits = v @ Wc + bc ----------
__global__ void final_kernel(const float* __restrict__ out1,
                             const float* __restrict__ mu, const float* __restrict__ rsig,
                             const float* __restrict__ gamma, const float* __restrict__ beta,
                             const float* __restrict__ Wc, const float* __restrict__ bc,
                             float* __restrict__ out, int N) {
    int n = blockIdx.x * 256 + threadIdx.x;
    if (n >= N) return;
    float l0 = bc[0], l1 = bc[1];
#pragma unroll
    for (int c = 0; c < 16; c++) {
        float v = (out1[(size_t)n * 16 + c] - mu[c]) * rsig[c] * gamma[c] + beta[c];
        l0 += v * Wc[c * 2 + 0];
        l1 += v * Wc[c * 2 + 1];
    }
    out[(size_t)n * 2 + 0] = l0;
    out[(size_t)n * 2 + 1] = l1;
}

// ---------- launcher ----------
extern "C" void kernel_launch(void* const* d_in, const int* in_sizes, int n_in,
                              void* d_out, int out_size, void* d_ws, size_t ws_size,
                              hipStream_t stream) {
    const float* x   = (const float*)d_in[0];
    const int*   ei  = (const int*)d_in[1];
    const float* W0  = (const float*)d_in[2];
    const float* as0 = (const float*)d_in[3];
    const float* ad0 = (const float*)d_in[4];
    // d_in[5] = b0: cancelled exactly by the following batch-norm's mean subtraction
    const float* g0  = (const float*)d_in[6];
    const float* be0 = (const float*)d_in[7];
    const float* W1  = (const float*)d_in[8];
    const float* as1 = (const float*)d_in[9];
    const float* ad1 = (const float*)d_in[10];
    // d_in[11] = b1: cancelled by BN as well
    const float* g1  = (const float*)d_in[12];
    const float* be1 = (const float*)d_in[13];
    const float* Wc  = (const float*)d_in[14];
    const float* bc  = (const float*)d_in[15];
    float* out = (float*)d_out;

    int N = in_sizes[0] / 128;
    int E = in_sizes[1] / 2;
    int Etot = E + N;

    // workspace layout
    char* ws = (char*)d_ws;
    size_t off = 0;
    auto walloc = [&](size_t bytes) -> void* {
        void* p = ws + off;
        off += (bytes + 255) & ~(size_t)255;
        return p;
    };
    float* A      = (float*)walloc((size_t)N * 128 * 4);
    float* B      = (float*)walloc((size_t)N * 128 * 4);
    float* a_src  = (float*)walloc((size_t)N * 8 * 4);
    float* a_dst  = (float*)walloc((size_t)N * 8 * 4);
    float* out1   = (float*)walloc((size_t)N * 16 * 4);
    int*   counts = (int*)walloc((size_t)N * 4);
    int*   fill   = (int*)walloc((size_t)N * 4);
    int*   rowptr = (int*)walloc((size_t)(N + 1) * 4);
    int*   ssrc   = (int*)walloc((size_t)Etot * 4);
    float* stats  = (float*)walloc(4 * 128 * 4);
    float* sums = stats, * sumsq = stats + 128, * mu = stats + 256, * rsig = stats + 384;

    dim3 b256(256);
    int gN64   = (N + 63) / 64;
    int gNH    = (N * 8 + 255) / 256;
    int gE     = (Etot + 255) / 256;
    int gAgg   = (N + 3) / 4;
    int gElem4 = (int)(((long)N * 32 + 255) / 256);
    int gStats = (N + 127) / 128;

    // ---- CSR build (once; same graph for both layers) ----
    hipMemsetAsync(counts, 0, (size_t)N * 4, stream);
    hipMemsetAsync(fill, 0, (size_t)N * 4, stream);
    hist_kernel<<<gE, b256, 0, stream>>>(ei, E, Etot, counts);
    scan_kernel<<<1, 1024, 0, stream>>>(counts, rowptr, N);
    scatter_kernel<<<gE, b256, 0, stream>>>(ei, E, Etot, rowptr, fill, ssrc);

    // ---- layer 0 ----
    gemm128<<<gN64, b256, 0, stream>>>(x, W0, A, N);                  // A = h0
    att_kernel<<<gNH, b256, 0, stream>>>(A, as0, ad0, a_src, a_dst, N);
    agg_kernel<<<gAgg, b256, 0, stream>>>(rowptr, ssrc, a_src, a_dst, A, B, N);  // B = agg0
    hipMemsetAsync(sums, 0, 2 * 128 * 4, stream);
    stats_kernel<<<gStats, b256, 0, stream>>>(B, N, 128, sums, sumsq, 128);
    finalize_stats<<<1, 128, 0, stream>>>(sums, sumsq, mu, rsig, 128, 1.0f / N);
    bn_elu_kernel<<<gElem4, b256, 0, stream>>>(B, mu, rsig, g0, be0, A, (long)N * 32); // A = h1_in

    // ---- layer 1 ----
    gemm128<<<gN64, b256, 0, stream>>>(A, W1, B, N);                  // B = h1
    att_kernel<<<gNH, b256, 0, stream>>>(B, as1, ad1, a_src, a_dst, N);
    agg_kernel<<<gAgg, b256, 0, stream>>>(rowptr, ssrc, a_src, a_dst, B, A, N);  // A = agg1
    headmean_kernel<<<(N * 4 + 255) / 256, b256, 0, stream>>>(A, out1, N);
    hipMemsetAsync(sums, 0, 2 * 128 * 4, stream);
    stats_kernel<<<gStats, b256, 0, stream>>>(out1, N, 16, sums, sumsq, 128);
    finalize_stats<<<1, 16, 0, stream>>>(sums, sumsq, mu, rsig, 16, 1.0f / N);
    final_kernel<<<(N + 255) / 256, b256, 0, stream>>>(out1, mu, rsig, g1, be1, Wc, bc, out, N);
}

// Round 3
// 720.551 us; speedup vs baseline: 6.3213x; 1.2121x over previous
//
#include <hip/hip_runtime.h>
#include <math.h>

#define NEG_SLOPE 0.2f
#define BN_EPS 1e-5f

// ---------- helpers ----------

__device__ __forceinline__ void edge_sd(const int* __restrict__ ei, int E, int eid, int& s, int& d) {
    if (eid < E) { s = ei[eid]; d = ei[E + eid]; }
    else         { s = d = eid - E; }   // self-loops appended after the E real edges
}

__device__ __forceinline__ float lrelu(float v) { return v > 0.f ? v : NEG_SLOPE * v; }

// ---------- GEMM: Y[N,128] = X[N,128] @ W[128,128] ----------
__global__ __launch_bounds__(256) void gemm128(const float* __restrict__ X,
                                               const float* __restrict__ W,
                                               float* __restrict__ Y, int Nrows) {
    __shared__ float xs[64 * 128];
    int bm = blockIdx.x * 64;
    int tid = threadIdx.x;

    const float4* Xv = (const float4*)(X + (size_t)bm * 128);
    float4* xsv = (float4*)xs;
    for (int i = tid; i < 64 * 32; i += 256) {
        int row = i >> 5;
        xsv[i] = (bm + row < Nrows) ? Xv[i] : make_float4(0.f, 0.f, 0.f, 0.f);
    }
    __syncthreads();

    int cq = tid & 31;   // column quad: cols cq*4..cq*4+3
    int rg = tid >> 5;   // row group: rows rg*8..rg*8+7

    float acc[8][4];
#pragma unroll
    for (int r = 0; r < 8; r++)
#pragma unroll
        for (int j = 0; j < 4; j++) acc[r][j] = 0.f;

    const float* xbase = xs + (rg * 8) * 128;
#pragma unroll 4
    for (int k = 0; k < 128; k++) {
        float4 w4 = *(const float4*)(W + k * 128 + cq * 4);
#pragma unroll
        for (int r = 0; r < 8; r++) {
            float xv = xbase[r * 128 + k];
            acc[r][0] += xv * w4.x;
            acc[r][1] += xv * w4.y;
            acc[r][2] += xv * w4.z;
            acc[r][3] += xv * w4.w;
        }
    }
#pragma unroll
    for (int r = 0; r < 8; r++) {
        int row = bm + rg * 8 + r;
        if (row < Nrows)
            *(float4*)(Y + (size_t)row * 128 + cq * 4) =
                make_float4(acc[r][0], acc[r][1], acc[r][2], acc[r][3]);
    }
}

// ---------- attention logits per node: a_src[n,h], a_dst[n,h] ----------
__global__ void att_kernel(const float* __restrict__ Hm,
                           const float* __restrict__ att_s,
                           const float* __restrict__ att_d,
                           float* __restrict__ a_src, float* __restrict__ a_dst, int N) {
    int idx = blockIdx.x * 256 + threadIdx.x;   // n*8 + h
    if (idx >= N * 8) return;
    int n = idx >> 3, h = idx & 7;
    const float* hp = Hm + (size_t)n * 128 + h * 16;
    float ss = 0.f, sd = 0.f;
#pragma unroll
    for (int c = 0; c < 16; c++) {
        float v = hp[c];
        ss += v * att_s[h * 16 + c];
        sd += v * att_d[h * 16 + c];
    }
    a_src[idx] = ss;
    a_dst[idx] = sd;
}

// ---------- CSR build: histogram of dst ----------
__global__ void hist_kernel(const int* __restrict__ ei, int E, int Etot,
                            int* __restrict__ counts) {
    int eid = blockIdx.x * 256 + threadIdx.x;
    if (eid >= Etot) return;
    int s, d;
    edge_sd(ei, E, eid, s, d);
    atomicAdd(&counts[d], 1);
}

// ---------- CSR build: single-block exclusive scan over counts -> rowptr ----------
__global__ __launch_bounds__(1024) void scan_kernel(const int* __restrict__ counts,
                                                    int* __restrict__ rowptr, int N) {
    __shared__ int wsum[16];
    __shared__ int carry;
    int tid = threadIdx.x, lane = tid & 63, wid = tid >> 6;
    if (tid == 0) { carry = 0; rowptr[0] = 0; }
    __syncthreads();
    for (int base = 0; base < N; base += 1024) {
        int idx = base + tid;
        int incl = (idx < N) ? counts[idx] : 0;
#pragma unroll
        for (int off = 1; off < 64; off <<= 1) {
            int t = __shfl_up(incl, off);
            if (lane >= off) incl += t;
        }
        if (lane == 63) wsum[wid] = incl;
        __syncthreads();
        int woff = 0;
        for (int w = 0; w < wid; w++) woff += wsum[w];
        int c = carry;
        if (idx < N) rowptr[idx + 1] = c + woff + incl;
        __syncthreads();
        if (tid == 0) {
            int t = 0;
            for (int w = 0; w < 16; w++) t += wsum[w];
            carry = c + t;
        }
        __syncthreads();
    }
}

// ---------- CSR build: scatter src ids into dst-sorted order ----------
__global__ void scatter_kernel(const int* __restrict__ ei, int E, int Etot,
                               const int* __restrict__ rowptr, int* __restrict__ fill,
                               int* __restrict__ ssrc) {
    int eid = blockIdx.x * 256 + threadIdx.x;
    if (eid >= Etot) return;
    int s, d;
    edge_sd(ei, E, eid, s, d);
    int pos = rowptr[d] + atomicAdd(&fill[d], 1);
    ssrc[pos] = s;
}

// ---------- fused softmax + aggregation: one wave per destination node ----------
__global__ __launch_bounds__(256) void agg_kernel(const int* __restrict__ rowptr,
                                                  const int* __restrict__ ssrc,
                                                  const float* __restrict__ a_src,
                                                  const float* __restrict__ a_dst,
                                                  const float* __restrict__ Hfeat,
                                                  float* __restrict__ outbuf, int N) {
    int wid = threadIdx.x >> 6;
    int dst = blockIdx.x * 4 + wid;
    if (dst >= N) return;
    int lane = threadIdx.x & 63;
    int h = lane >> 3;
    int start = rowptr[dst], end = rowptr[dst + 1];
    float adst = a_dst[dst * 8 + h];

    // phase 1: online softmax (max + sum of exp), 8 lanes per head, stride 8
    float mloc = -1e30f, sloc = 0.f;
    for (int i = start + (lane & 7); i < end; i += 8) {
        int s = ssrc[i];
        float e = lrelu(a_src[s * 8 + h] + adst);
        float nm = fmaxf(mloc, e);
        sloc = sloc * __expf(mloc - nm) + __expf(e - nm);
        mloc = nm;
    }
#pragma unroll
    for (int off = 1; off < 8; off <<= 1) {
        float om = __shfl_xor(mloc, off);
        float os = __shfl_xor(sloc, off);
        float nm = fmaxf(mloc, om);
        sloc = sloc * __expf(mloc - nm) + os * __expf(om - nm);
        mloc = nm;
    }
    float inv = 1.f / (sloc + 1e-16f);

    // phase 2: weighted feature accumulation, all 64 lanes per edge (float2 each)
    float acc0 = 0.f, acc1 = 0.f;
    int f = lane * 2;
    for (int i = start; i < end; i++) {
        int s = ssrc[i];
        float e = lrelu(a_src[s * 8 + h] + adst);
        float alpha = __expf(e - mloc) * inv;
        float2 hv = *(const float2*)(Hfeat + (size_t)s * 128 + f);
        acc0 += hv.x * alpha;
        acc1 += hv.y * alpha;
    }
    *(float2*)(outbuf + (size_t)dst * 128 + f) = make_float2(acc0, acc1);
}

// ---------- batch-norm stats: two-stage deterministic reduction (NO atomics) ----------
// Stage 1: each block LDS-reduces its row chunk -> partial[blk][2C].
template <int C>
__global__ __launch_bounds__(256) void stats_part_kernel(const float* __restrict__ X, int Nrows,
                                                         float* __restrict__ partial,
                                                         int rows_per_block) {
    constexpr int GSZ = 256 / C;
    __shared__ float ls[256], lq[256];
    int c = threadIdx.x % C;
    int g = threadIdx.x / C;
    long base = (long)blockIdx.x * rows_per_block;
    long endr = base + rows_per_block;
    if (endr > Nrows) endr = Nrows;
    float s = 0.f, q = 0.f;
    for (long r = base + g; r < endr; r += GSZ) {
        float v = X[r * C + c];
        s += v;
        q += v * v;
    }
    ls[threadIdx.x] = s;
    lq[threadIdx.x] = q;
    __syncthreads();
#pragma unroll
    for (int st = GSZ / 2; st > 0; st >>= 1) {
        if (g < st) {
            ls[threadIdx.x] += ls[threadIdx.x + st * C];
            lq[threadIdx.x] += lq[threadIdx.x + st * C];
        }
        __syncthreads();
    }
    if (g == 0) {
        partial[(size_t)blockIdx.x * (2 * C) + c] = ls[c];
        partial[(size_t)blockIdx.x * (2 * C) + C + c] = lq[c];
    }
}

// Stage 2: reduce partials across blocks, emit mu/rsig.
template <int C>
__global__ void stats_final_kernel(const float* __restrict__ partial, int nblk, float invN,
                                   float* __restrict__ mu, float* __restrict__ rsig) {
    int c = threadIdx.x;
    if (c >= C) return;
    float s = 0.f, q = 0.f;
    for (int b = 0; b < nblk; b++) {
        s += partial[(size_t)b * (2 * C) + c];
        q += partial[(size_t)b * (2 * C) + C + c];
    }
    float m_ = s * invN;
    float v = q * invN - m_ * m_;
    mu[c] = m_;
    rsig[c] = rsqrtf(v + BN_EPS);
}

// ---------- BN + ELU elementwise (128 cols, float4) ----------
__global__ void bn_elu_kernel(const float* __restrict__ X,
                              const float* __restrict__ mu, const float* __restrict__ rsig,
                              const float* __restrict__ gamma, const float* __restrict__ beta,
                              float* __restrict__ Y, long total4) {
    long i = (long)blockIdx.x * 256 + threadIdx.x;
    if (i >= total4) return;
    int c4 = (int)(i & 31) * 4;
    float4 x = ((const float4*)X)[i];
    float r[4] = {x.x, x.y, x.z, x.w};
#pragma unroll
    for (int j = 0; j < 4; j++) {
        int c = c4 + j;
        float v = (r[j] - mu[c]) * rsig[c] * gamma[c] + beta[c];
        r[j] = v > 0.f ? v : expm1f(v);   // ELU
    }
    ((float4*)Y)[i] = make_float4(r[0], r[1], r[2], r[3]);
}

// ---------- mean over heads: [N,8,16] -> [N,16] ----------
__global__ void headmean_kernel(const float* __restrict__ X, float* __restrict__ out1, int N) {
    int idx = blockIdx.x * 256 + threadIdx.x;   // n*4 + c4
    if (idx >= N * 4) return;
    int n = idx >> 2, c4 = (idx & 3) * 4;
    float4 acc = make_float4(0.f, 0.f, 0.f, 0.f);
#pragma unroll
    for (int h = 0; h < 8; h++) {
        float4 v = *(const float4*)(X + (size_t)n * 128 + h * 16 + c4);
        acc.x += v.x; acc.y += v.y; acc.z += v.z; acc.w += v.w;
    }
    acc.x *= 0.125f; acc.y *= 0.125f; acc.z *= 0.125f; acc.w *= 0.125f;
    *(float4*)(out1 + (size_t)n * 16 + c4) = acc;
}

// ---------- final: BN(16) + logits = v @ Wc + bc ----------
__global__ void final_kernel(const float* __restrict__ out1,
                             const float* __restrict__ mu, const float* __restrict__ rsig,
                             const float* __restrict__ gamma, const float* __restrict__ beta,
                             const float* __restrict__ Wc, const float* __restrict__ bc,
                             float* __restrict__ out, int N) {
    int n = blockIdx.x * 256 + threadIdx.x;
    if (n >= N) return;
    float l0 = bc[0], l1 = bc[1];
#pragma unroll
    for (int c = 0; c < 16; c++) {
        float v = (out1[(size_t)n * 16 + c] - mu[c]) * rsig[c] * gamma[c] + beta[c];
        l0 += v * Wc[c * 2 + 0];
        l1 += v * Wc[c * 2 + 1];
    }
    out[(size_t)n * 2 + 0] = l0;
    out[(size_t)n * 2 + 1] = l1;
}

// ---------- launcher ----------
extern "C" void kernel_launch(void* const* d_in, const int* in_sizes, int n_in,
                              void* d_out, int out_size, void* d_ws, size_t ws_size,
                              hipStream_t stream) {
    const float* x   = (const float*)d_in[0];
    const int*   ei  = (const int*)d_in[1];
    const float* W0  = (const float*)d_in[2];
    const float* as0 = (const float*)d_in[3];
    const float* ad0 = (const float*)d_in[4];
    // d_in[5] = b0: cancelled exactly by the following batch-norm's mean subtraction
    const float* g0  = (const float*)d_in[6];
    const float* be0 = (const float*)d_in[7];
    const float* W1  = (const float*)d_in[8];
    const float* as1 = (const float*)d_in[9];
    const float* ad1 = (const float*)d_in[10];
    // d_in[11] = b1: cancelled by BN as well
    const float* g1  = (const float*)d_in[12];
    const float* be1 = (const float*)d_in[13];
    const float* Wc  = (const float*)d_in[14];
    const float* bc  = (const float*)d_in[15];
    float* out = (float*)d_out;

    int N = in_sizes[0] / 128;
    int E = in_sizes[1] / 2;
    int Etot = E + N;

    // workspace layout
    char* ws = (char*)d_ws;
    size_t off = 0;
    auto walloc = [&](size_t bytes) -> void* {
        void* p = ws + off;
        off += (bytes + 255) & ~(size_t)255;
        return p;
    };
    float* A       = (float*)walloc((size_t)N * 128 * 4);
    float* B       = (float*)walloc((size_t)N * 128 * 4);
    float* a_src   = (float*)walloc((size_t)N * 8 * 4);
    float* a_dst   = (float*)walloc((size_t)N * 8 * 4);
    float* out1    = (float*)walloc((size_t)N * 16 * 4);
    int*   counts  = (int*)walloc((size_t)N * 4);
    int*   fill    = (int*)walloc((size_t)N * 4);
    int*   rowptr  = (int*)walloc((size_t)(N + 1) * 4);
    int*   ssrc    = (int*)walloc((size_t)Etot * 4);
    float* partial = (float*)walloc((size_t)256 * 256 * 4);   // [256 blocks][2*128]
    float* stats   = (float*)walloc(2 * 128 * 4);
    float* mu = stats, * rsig = stats + 128;

    dim3 b256(256);
    int gN64    = (N + 63) / 64;
    int gNH     = (N * 8 + 255) / 256;
    int gE      = (Etot + 255) / 256;
    int gAgg    = (N + 3) / 4;
    int gElem4  = (int)(((long)N * 32 + 255) / 256);
    const int SBLK = 256;
    int rpb = (N + SBLK - 1) / SBLK;

    // ---- CSR build (once; same graph for both layers) ----
    hipMemsetAsync(counts, 0, (size_t)N * 4, stream);
    hipMemsetAsync(fill, 0, (size_t)N * 4, stream);
    hist_kernel<<<gE, b256, 0, stream>>>(ei, E, Etot, counts);
    scan_kernel<<<1, 1024, 0, stream>>>(counts, rowptr, N);
    scatter_kernel<<<gE, b256, 0, stream>>>(ei, E, Etot, rowptr, fill, ssrc);

    // ---- layer 0 ----
    gemm128<<<gN64, b256, 0, stream>>>(x, W0, A, N);                  // A = h0
    att_kernel<<<gNH, b256, 0, stream>>>(A, as0, ad0, a_src, a_dst, N);
    agg_kernel<<<gAgg, b256, 0, stream>>>(rowptr, ssrc, a_src, a_dst, A, B, N);  // B = agg0
    stats_part_kernel<128><<<SBLK, b256, 0, stream>>>(B, N, partial, rpb);
    stats_final_kernel<128><<<1, 128, 0, stream>>>(partial, SBLK, 1.0f / N, mu, rsig);
    bn_elu_kernel<<<gElem4, b256, 0, stream>>>(B, mu, rsig, g0, be0, A, (long)N * 32); // A = h1_in

    // ---- layer 1 ----
    gemm128<<<gN64, b256, 0, stream>>>(A, W1, B, N);                  // B = h1
    att_kernel<<<gNH, b256, 0, stream>>>(B, as1, ad1, a_src, a_dst, N);
    agg_kernel<<<gAgg, b256, 0, stream>>>(rowptr, ssrc, a_src, a_dst, B, A, N);  // A = agg1
    headmean_kernel<<<(N * 4 + 255) / 256, b256, 0, stream>>>(A, out1, N);
    stats_part_kernel<16><<<SBLK, b256, 0, stream>>>(out1, N, partial, rpb);
    stats_final_kernel<16><<<1, 16, 0, stream>>>(partial, SBLK, 1.0f / N, mu, rsig);
    final_kernel<<<(N + 255) / 256, b256, 0, stream>>>(out1, mu, rsig, g1, be1, Wc, bc, out, N);
}

// Round 4
// 642.468 us; speedup vs baseline: 7.0895x; 1.1215x over previous
//
#include <hip/hip_runtime.h>
#include <math.h>

#define NEG_SLOPE 0.2f
#define BN_EPS 1e-5f

// ---------- helpers ----------

__device__ __forceinline__ void edge_sd(const int* __restrict__ ei, int E, int eid, int& s, int& d) {
    if (eid < E) { s = ei[eid]; d = ei[E + eid]; }
    else         { s = d = eid - E; }   // self-loops appended after the E real edges
}

__device__ __forceinline__ float lrelu(float v) { return v > 0.f ? v : NEG_SLOPE * v; }

// round-to-nearest-even fp32 -> bf16 bits
__device__ __forceinline__ unsigned short f2bf(float f) {
    unsigned u = __float_as_uint(f);
    u += 0x7fffu + ((u >> 16) & 1u);
    return (unsigned short)(u >> 16);
}

// ---------- GEMM: Y[N,128] = X[N,128] @ W[128,128]; also writes bf16 shadow ----------
__global__ __launch_bounds__(256) void gemm128(const float* __restrict__ X,
                                               const float* __restrict__ W,
                                               float* __restrict__ Y,
                                               unsigned short* __restrict__ Ybf, int Nrows) {
    __shared__ float xs[64 * 128];
    int bm = blockIdx.x * 64;
    int tid = threadIdx.x;

    const float4* Xv = (const float4*)(X + (size_t)bm * 128);
    float4* xsv = (float4*)xs;
    for (int i = tid; i < 64 * 32; i += 256) {
        int row = i >> 5;
        xsv[i] = (bm + row < Nrows) ? Xv[i] : make_float4(0.f, 0.f, 0.f, 0.f);
    }
    __syncthreads();

    int cq = tid & 31;   // column quad: cols cq*4..cq*4+3
    int rg = tid >> 5;   // row group: rows rg*8..rg*8+7

    float acc[8][4];
#pragma unroll
    for (int r = 0; r < 8; r++)
#pragma unroll
        for (int j = 0; j < 4; j++) acc[r][j] = 0.f;

    const float* xbase = xs + (rg * 8) * 128;
#pragma unroll 4
    for (int k = 0; k < 128; k++) {
        float4 w4 = *(const float4*)(W + k * 128 + cq * 4);
#pragma unroll
        for (int r = 0; r < 8; r++) {
            float xv = xbase[r * 128 + k];
            acc[r][0] += xv * w4.x;
            acc[r][1] += xv * w4.y;
            acc[r][2] += xv * w4.z;
            acc[r][3] += xv * w4.w;
        }
    }
#pragma unroll
    for (int r = 0; r < 8; r++) {
        int row = bm + rg * 8 + r;
        if (row < Nrows) {
            *(float4*)(Y + (size_t)row * 128 + cq * 4) =
                make_float4(acc[r][0], acc[r][1], acc[r][2], acc[r][3]);
            ushort4 pk;
            pk.x = f2bf(acc[r][0]);
            pk.y = f2bf(acc[r][1]);
            pk.z = f2bf(acc[r][2]);
            pk.w = f2bf(acc[r][3]);
            *(ushort4*)(Ybf + (size_t)row * 128 + cq * 4) = pk;
        }
    }
}

// ---------- attention logits per node: a_src[n,h], a_dst[n,h] ----------
__global__ void att_kernel(const float* __restrict__ Hm,
                           const float* __restrict__ att_s,
                           const float* __restrict__ att_d,
                           float* __restrict__ a_src, float* __restrict__ a_dst, int N) {
    int idx = blockIdx.x * 256 + threadIdx.x;   // n*8 + h
    if (idx >= N * 8) return;
    int n = idx >> 3, h = idx & 7;
    const float* hp = Hm + (size_t)n * 128 + h * 16;
    float ss = 0.f, sd = 0.f;
#pragma unroll
    for (int c = 0; c < 16; c++) {
        float v = hp[c];
        ss += v * att_s[h * 16 + c];
        sd += v * att_d[h * 16 + c];
    }
    a_src[idx] = ss;
    a_dst[idx] = sd;
}

// ---------- CSR build: histogram of dst ----------
__global__ void hist_kernel(const int* __restrict__ ei, int E, int Etot,
                            int* __restrict__ counts) {
    int eid = blockIdx.x * 256 + threadIdx.x;
    if (eid >= Etot) return;
    int s, d;
    edge_sd(ei, E, eid, s, d);
    atomicAdd(&counts[d], 1);
}

// ---------- CSR build: parallel 3-stage exclusive scan ----------
// Stage A: per-chunk (1024 counts) sums.
__global__ __launch_bounds__(256) void chunksum_kernel(const int* __restrict__ counts,
                                                       int* __restrict__ csum, int N) {
    __shared__ int red[256];
    int base = blockIdx.x * 1024;
    int s = 0;
    for (int i = threadIdx.x; i < 1024; i += 256) {
        int idx = base + i;
        s += (idx < N) ? counts[idx] : 0;
    }
    red[threadIdx.x] = s;
    __syncthreads();
#pragma unroll
    for (int st = 128; st > 0; st >>= 1) {
        if (threadIdx.x < st) red[threadIdx.x] += red[threadIdx.x + st];
        __syncthreads();
    }
    if (threadIdx.x == 0) csum[blockIdx.x] = red[0];
}

// Stage B: exclusive scan of chunk sums (single wave, nchunk <= 64).
__global__ void chunkscan_kernel(int* __restrict__ csum, int nchunk) {
    int lane = threadIdx.x;
    int v = (lane < nchunk) ? csum[lane] : 0;
    int incl = v;
#pragma unroll
    for (int off = 1; off < 64; off <<= 1) {
        int t = __shfl_up(incl, off);
        if (lane >= off) incl += t;
    }
    if (lane < nchunk) csum[lane] = incl - v;
}

// Stage C: per-chunk scan + chunk offset -> rowptr.
__global__ __launch_bounds__(1024) void scanfinal_kernel(const int* __restrict__ counts,
                                                         const int* __restrict__ csum,
                                                         int* __restrict__ rowptr, int N) {
    __shared__ int wsum[16], woff_s[16];
    int tid = threadIdx.x, lane = tid & 63, wid = tid >> 6;
    int idx = blockIdx.x * 1024 + tid;
    int v = (idx < N) ? counts[idx] : 0;
    int incl = v;
#pragma unroll
    for (int off = 1; off < 64; off <<= 1) {
        int t = __shfl_up(incl, off);
        if (lane >= off) incl += t;
    }
    if (lane == 63) wsum[wid] = incl;
    __syncthreads();
    if (wid == 0 && lane < 16) {
        int w = wsum[lane], iw = w;
#pragma unroll
        for (int off = 1; off < 16; off <<= 1) {
            int t = __shfl_up(iw, off);
            if (lane >= off) iw += t;
        }
        woff_s[lane] = iw - w;
    }
    __syncthreads();
    if (idx < N) rowptr[idx + 1] = csum[blockIdx.x] + woff_s[wid] + incl;
    if (blockIdx.x == 0 && tid == 0) rowptr[0] = 0;
}

// ---------- CSR build: scatter src ids into dst-sorted order ----------
__global__ void scatter_kernel(const int* __restrict__ ei, int E, int Etot,
                               const int* __restrict__ rowptr, int* __restrict__ fill,
                               int* __restrict__ ssrc) {
    int eid = blockIdx.x * 256 + threadIdx.x;
    if (eid >= Etot) return;
    int s, d;
    edge_sd(ei, E, eid, s, d);
    int pos = rowptr[d] + atomicAdd(&fill[d], 1);
    ssrc[pos] = s;
}

// ---------- fused softmax + aggregation: SINGLE edge pass, one wave per dst ----------
// No max subtraction (exact softmax up to fp rounding: e is O(+-10), exp safe in fp32).
// acc = sum exp(e)*h_bf16[src]; den = sum exp(e); out = acc/den.
__global__ __launch_bounds__(256) void agg_kernel(const int* __restrict__ rowptr,
                                                  const int* __restrict__ ssrc,
                                                  const float* __restrict__ a_src,
                                                  const float* __restrict__ a_dst,
                                                  const unsigned short* __restrict__ Hbf,
                                                  float* __restrict__ outbuf, int N) {
    int wid = threadIdx.x >> 6;
    int dst = blockIdx.x * 4 + wid;
    if (dst >= N) return;
    int lane = threadIdx.x & 63;
    int h = lane >> 3;          // head of this lane's feature pair (f/16)
    int f = lane * 2;           // features f, f+1
    int start = rowptr[dst], end = rowptr[dst + 1];
    float adst = a_dst[dst * 8 + h];

    float acc0 = 0.f, acc1 = 0.f, den = 0.f;
    int s = (start < end) ? ssrc[start] : 0;
    for (int i = start; i < end; i++) {
        int sn = (i + 1 < end) ? ssrc[i + 1] : 0;   // prefetch next src id
        float e = lrelu(a_src[s * 8 + h] + adst);
        float w = __expf(e);
        unsigned u = *(const unsigned*)(Hbf + (size_t)s * 128 + f);
        float hx = __uint_as_float(u << 16);
        float hy = __uint_as_float(u & 0xffff0000u);
        acc0 += w * hx;
        acc1 += w * hy;
        den += w;
        s = sn;
    }
    float inv = 1.f / (den + 1e-16f);
    *(float2*)(outbuf + (size_t)dst * 128 + f) = make_float2(acc0 * inv, acc1 * inv);
}

// ---------- batch-norm stats: two-stage deterministic reduction (NO atomics) ----------
template <int C>
__global__ __launch_bounds__(256) void stats_part_kernel(const float* __restrict__ X, int Nrows,
                                                         float* __restrict__ partial,
                                                         int rows_per_block) {
    constexpr int GSZ = 256 / C;
    __shared__ float ls[256], lq[256];
    int c = threadIdx.x % C;
    int g = threadIdx.x / C;
    long base = (long)blockIdx.x * rows_per_block;
    long endr = base + rows_per_block;
    if (endr > Nrows) endr = Nrows;
    float s = 0.f, q = 0.f;
    for (long r = base + g; r < endr; r += GSZ) {
        float v = X[r * C + c];
        s += v;
        q += v * v;
    }
    ls[threadIdx.x] = s;
    lq[threadIdx.x] = q;
    __syncthreads();
#pragma unroll
    for (int st = GSZ / 2; st > 0; st >>= 1) {
        if (g < st) {
            ls[threadIdx.x] += ls[threadIdx.x + st * C];
            lq[threadIdx.x] += lq[threadIdx.x + st * C];
        }
        __syncthreads();
    }
    if (g == 0) {
        partial[(size_t)blockIdx.x * (2 * C) + c] = ls[c];
        partial[(size_t)blockIdx.x * (2 * C) + C + c] = lq[c];
    }
}

template <int C>
__global__ void stats_final_kernel(const float* __restrict__ partial, int nblk, float invN,
                                   float* __restrict__ mu, float* __restrict__ rsig) {
    int c = threadIdx.x;
    if (c >= C) return;
    float s = 0.f, q = 0.f;
    for (int b = 0; b < nblk; b++) {
        s += partial[(size_t)b * (2 * C) + c];
        q += partial[(size_t)b * (2 * C) + C + c];
    }
    float m_ = s * invN;
    float v = q * invN - m_ * m_;
    mu[c] = m_;
    rsig[c] = rsqrtf(v + BN_EPS);
}

// ---------- BN + ELU elementwise (128 cols, float4) ----------
__global__ void bn_elu_kernel(const float* __restrict__ X,
                              const float* __restrict__ mu, const float* __restrict__ rsig,
                              const float* __restrict__ gamma, const float* __restrict__ beta,
                              float* __restrict__ Y, long total4) {
    long i = (long)blockIdx.x * 256 + threadIdx.x;
    if (i >= total4) return;
    int c4 = (int)(i & 31) * 4;
    float4 x = ((const float4*)X)[i];
    float r[4] = {x.x, x.y, x.z, x.w};
#pragma unroll
    for (int j = 0; j < 4; j++) {
        int c = c4 + j;
        float v = (r[j] - mu[c]) * rsig[c] * gamma[c] + beta[c];
        r[j] = v > 0.f ? v : expm1f(v);   // ELU
    }
    ((float4*)Y)[i] = make_float4(r[0], r[1], r[2], r[3]);
}

// ---------- mean over heads: [N,8,16] -> [N,16] ----------
__global__ void headmean_kernel(const float* __restrict__ X, float* __restrict__ out1, int N) {
    int idx = blockIdx.x * 256 + threadIdx.x;   // n*4 + c4
    if (idx >= N * 4) return;
    int n = idx >> 2, c4 = (idx & 3) * 4;
    float4 acc = make_float4(0.f, 0.f, 0.f, 0.f);
#pragma unroll
    for (int h = 0; h < 8; h++) {
        float4 v = *(const float4*)(X + (size_t)n * 128 + h * 16 + c4);
        acc.x += v.x; acc.y += v.y; acc.z += v.z; acc.w += v.w;
    }
    acc.x *= 0.125f; acc.y *= 0.125f; acc.z *= 0.125f; acc.w *= 0.125f;
    *(float4*)(out1 + (size_t)n * 16 + c4) = acc;
}

// ---------- final: BN(16) + logits = v @ Wc + bc ----------
__global__ void final_kernel(const float* __restrict__ out1,
                             const float* __restrict__ mu, const float* __restrict__ rsig,
                             const float* __restrict__ gamma, const float* __restrict__ beta,
                             const float* __restrict__ Wc, const float* __restrict__ bc,
                             float* __restrict__ out, int N) {
    int n = blockIdx.x * 256 + threadIdx.x;
    if (n >= N) return;
    float l0 = bc[0], l1 = bc[1];
#pragma unroll
    for (int c = 0; c < 16; c++) {
        float v = (out1[(size_t)n * 16 + c] - mu[c]) * rsig[c] * gamma[c] + beta[c];
        l0 += v * Wc[c * 2 + 0];
        l1 += v * Wc[c * 2 + 1];
    }
    out[(size_t)n * 2 + 0] = l0;
    out[(size_t)n * 2 + 1] = l1;
}

// ---------- launcher ----------
extern "C" void kernel_launch(void* const* d_in, const int* in_sizes, int n_in,
                              void* d_out, int out_size, void* d_ws, size_t ws_size,
                              hipStream_t stream) {
    const float* x   = (const float*)d_in[0];
    const int*   ei  = (const int*)d_in[1];
    const float* W0  = (const float*)d_in[2];
    const float* as0 = (const float*)d_in[3];
    const float* ad0 = (const float*)d_in[4];
    // d_in[5] = b0: cancelled exactly by the following batch-norm's mean subtraction
    const float* g0  = (const float*)d_in[6];
    const float* be0 = (const float*)d_in[7];
    const float* W1  = (const float*)d_in[8];
    const float* as1 = (const float*)d_in[9];
    const float* ad1 = (const float*)d_in[10];
    // d_in[11] = b1: cancelled by BN as well
    const float* g1  = (const float*)d_in[12];
    const float* be1 = (const float*)d_in[13];
    const float* Wc  = (const float*)d_in[14];
    const float* bc  = (const float*)d_in[15];
    float* out = (float*)d_out;

    int N = in_sizes[0] / 128;
    int E = in_sizes[1] / 2;
    int Etot = E + N;

    // workspace layout
    char* ws = (char*)d_ws;
    size_t off = 0;
    auto walloc = [&](size_t bytes) -> void* {
        void* p = ws + off;
        off += (bytes + 255) & ~(size_t)255;
        return p;
    };
    float*          A       = (float*)walloc((size_t)N * 128 * 4);
    float*          B       = (float*)walloc((size_t)N * 128 * 4);
    unsigned short* Hbf     = (unsigned short*)walloc((size_t)N * 128 * 2);
    float*          a_src   = (float*)walloc((size_t)N * 8 * 4);
    float*          a_dst   = (float*)walloc((size_t)N * 8 * 4);
    float*          out1    = (float*)walloc((size_t)N * 16 * 4);
    int*            counts  = (int*)walloc((size_t)N * 4);
    int*            fill    = (int*)walloc((size_t)N * 4);
    int*            rowptr  = (int*)walloc((size_t)(N + 1) * 4);
    int*            csum    = (int*)walloc(64 * 4);
    int*            ssrc    = (int*)walloc((size_t)Etot * 4);
    float*          partial = (float*)walloc((size_t)256 * 256 * 4);   // [256 blocks][2*128]
    float*          stats   = (float*)walloc(2 * 128 * 4);
    float* mu = stats, * rsig = stats + 128;

    dim3 b256(256);
    int gN64    = (N + 63) / 64;
    int gNH     = (N * 8 + 255) / 256;
    int gE      = (Etot + 255) / 256;
    int gAgg    = (N + 3) / 4;
    int gElem4  = (int)(((long)N * 32 + 255) / 256);
    int nchunk  = (N + 1023) / 1024;
    const int SBLK = 256;
    int rpb = (N + SBLK - 1) / SBLK;

    // ---- CSR build (once; same graph for both layers) ----
    hipMemsetAsync(counts, 0, (size_t)N * 4, stream);
    hipMemsetAsync(fill, 0, (size_t)N * 4, stream);
    hist_kernel<<<gE, b256, 0, stream>>>(ei, E, Etot, counts);
    chunksum_kernel<<<nchunk, b256, 0, stream>>>(counts, csum, N);
    chunkscan_kernel<<<1, 64, 0, stream>>>(csum, nchunk);
    scanfinal_kernel<<<nchunk, 1024, 0, stream>>>(counts, csum, rowptr, N);
    scatter_kernel<<<gE, b256, 0, stream>>>(ei, E, Etot, rowptr, fill, ssrc);

    // ---- layer 0 ----
    gemm128<<<gN64, b256, 0, stream>>>(x, W0, A, Hbf, N);             // A = h0 (+ bf16 shadow)
    att_kernel<<<gNH, b256, 0, stream>>>(A, as0, ad0, a_src, a_dst, N);
    agg_kernel<<<gAgg, b256, 0, stream>>>(rowptr, ssrc, a_src, a_dst, Hbf, B, N);  // B = agg0
    stats_part_kernel<128><<<SBLK, b256, 0, stream>>>(B, N, partial, rpb);
    stats_final_kernel<128><<<1, 128, 0, stream>>>(partial, SBLK, 1.0f / N, mu, rsig);
    bn_elu_kernel<<<gElem4, b256, 0, stream>>>(B, mu, rsig, g0, be0, A, (long)N * 32); // A = h1_in

    // ---- layer 1 ----
    gemm128<<<gN64, b256, 0, stream>>>(A, W1, B, Hbf, N);             // B = h1 (+ bf16 shadow)
    att_kernel<<<gNH, b256, 0, stream>>>(B, as1, ad1, a_src, a_dst, N);
    agg_kernel<<<gAgg, b256, 0, stream>>>(rowptr, ssrc, a_src, a_dst, Hbf, A, N);  // A = agg1
    headmean_kernel<<<(N * 4 + 255) / 256, b256, 0, stream>>>(A, out1, N);
    stats_part_kernel<16><<<SBLK, b256, 0, stream>>>(out1, N, partial, rpb);
    stats_final_kernel<16><<<1, 16, 0, stream>>>(partial, SBLK, 1.0f / N, mu, rsig);
    final_kernel<<<(N + 255) / 256, b256, 0, stream>>>(out1, mu, rsig, g1, be1, Wc, bc, out, N);
}

// Round 5
// 544.339 us; speedup vs baseline: 8.3676x; 1.1803x over previous
//
#include <hip/hip_runtime.h>
#include <math.h>

#define NEG_SLOPE 0.2f
#define BN_EPS 1e-5f

// ---------- helpers ----------

__device__ __forceinline__ void edge_sd(const int* __restrict__ ei, int E, int eid, int& s, int& d) {
    if (eid < E) { s = ei[eid]; d = ei[E + eid]; }
    else         { s = d = eid - E; }   // self-loops appended after the E real edges
}

__device__ __forceinline__ float lrelu(float v) { return v > 0.f ? v : NEG_SLOPE * v; }

// round-to-nearest-even fp32 -> bf16 bits
__device__ __forceinline__ unsigned short f2bf(float f) {
    unsigned u = __float_as_uint(f);
    u += 0x7fffu + ((u >> 16) & 1u);
    return (unsigned short)(u >> 16);
}

// ---------- GEMM: Y[N,128] = X[N,128] @ W[128,128]; also writes bf16 shadow ----------
__global__ __launch_bounds__(256) void gemm128(const float* __restrict__ X,
                                               const float* __restrict__ W,
                                               float* __restrict__ Y,
                                               unsigned short* __restrict__ Ybf, int Nrows) {
    __shared__ float xs[64 * 128];
    int bm = blockIdx.x * 64;
    int tid = threadIdx.x;

    const float4* Xv = (const float4*)(X + (size_t)bm * 128);
    float4* xsv = (float4*)xs;
    for (int i = tid; i < 64 * 32; i += 256) {
        int row = i >> 5;
        xsv[i] = (bm + row < Nrows) ? Xv[i] : make_float4(0.f, 0.f, 0.f, 0.f);
    }
    __syncthreads();

    int cq = tid & 31;   // column quad: cols cq*4..cq*4+3
    int rg = tid >> 5;   // row group: rows rg*8..rg*8+7

    float acc[8][4];
#pragma unroll
    for (int r = 0; r < 8; r++)
#pragma unroll
        for (int j = 0; j < 4; j++) acc[r][j] = 0.f;

    const float* xbase = xs + (rg * 8) * 128;
#pragma unroll 4
    for (int k = 0; k < 128; k++) {
        float4 w4 = *(const float4*)(W + k * 128 + cq * 4);
#pragma unroll
        for (int r = 0; r < 8; r++) {
            float xv = xbase[r * 128 + k];
            acc[r][0] += xv * w4.x;
            acc[r][1] += xv * w4.y;
            acc[r][2] += xv * w4.z;
            acc[r][3] += xv * w4.w;
        }
    }
#pragma unroll
    for (int r = 0; r < 8; r++) {
        int row = bm + rg * 8 + r;
        if (row < Nrows) {
            *(float4*)(Y + (size_t)row * 128 + cq * 4) =
                make_float4(acc[r][0], acc[r][1], acc[r][2], acc[r][3]);
            ushort4 pk;
            pk.x = f2bf(acc[r][0]);
            pk.y = f2bf(acc[r][1]);
            pk.z = f2bf(acc[r][2]);
            pk.w = f2bf(acc[r][3]);
            *(ushort4*)(Ybf + (size_t)row * 128 + cq * 4) = pk;
        }
    }
}

// ---------- attention logits per node: a_src[n,h], a_dst[n,h] ----------
__global__ void att_kernel(const float* __restrict__ Hm,
                           const float* __restrict__ att_s,
                           const float* __restrict__ att_d,
                           float* __restrict__ a_src, float* __restrict__ a_dst, int N) {
    int idx = blockIdx.x * 256 + threadIdx.x;   // n*8 + h
    if (idx >= N * 8) return;
    int n = idx >> 3, h = idx & 7;
    const float* hp = Hm + (size_t)n * 128 + h * 16;
    float ss = 0.f, sd = 0.f;
#pragma unroll
    for (int c = 0; c < 16; c++) {
        float v = hp[c];
        ss += v * att_s[h * 16 + c];
        sd += v * att_d[h * 16 + c];
    }
    a_src[idx] = ss;
    a_dst[idx] = sd;
}

// ---------- CSR build: histogram of dst ----------
__global__ void hist_kernel(const int* __restrict__ ei, int E, int Etot,
                            int* __restrict__ counts) {
    int eid = blockIdx.x * 256 + threadIdx.x;
    if (eid >= Etot) return;
    int s, d;
    edge_sd(ei, E, eid, s, d);
    atomicAdd(&counts[d], 1);
}

// ---------- CSR build: parallel 3-stage exclusive scan ----------
__global__ __launch_bounds__(256) void chunksum_kernel(const int* __restrict__ counts,
                                                       int* __restrict__ csum, int N) {
    __shared__ int red[256];
    int base = blockIdx.x * 1024;
    int s = 0;
    for (int i = threadIdx.x; i < 1024; i += 256) {
        int idx = base + i;
        s += (idx < N) ? counts[idx] : 0;
    }
    red[threadIdx.x] = s;
    __syncthreads();
#pragma unroll
    for (int st = 128; st > 0; st >>= 1) {
        if (threadIdx.x < st) red[threadIdx.x] += red[threadIdx.x + st];
        __syncthreads();
    }
    if (threadIdx.x == 0) csum[blockIdx.x] = red[0];
}

__global__ void chunkscan_kernel(int* __restrict__ csum, int nchunk) {
    int lane = threadIdx.x;
    int v = (lane < nchunk) ? csum[lane] : 0;
    int incl = v;
#pragma unroll
    for (int off = 1; off < 64; off <<= 1) {
        int t = __shfl_up(incl, off);
        if (lane >= off) incl += t;
    }
    if (lane < nchunk) csum[lane] = incl - v;
}

__global__ __launch_bounds__(1024) void scanfinal_kernel(const int* __restrict__ counts,
                                                         const int* __restrict__ csum,
                                                         int* __restrict__ rowptr, int N) {
    __shared__ int wsum[16], woff_s[16];
    int tid = threadIdx.x, lane = tid & 63, wid = tid >> 6;
    int idx = blockIdx.x * 1024 + tid;
    int v = (idx < N) ? counts[idx] : 0;
    int incl = v;
#pragma unroll
    for (int off = 1; off < 64; off <<= 1) {
        int t = __shfl_up(incl, off);
        if (lane >= off) incl += t;
    }
    if (lane == 63) wsum[wid] = incl;
    __syncthreads();
    if (wid == 0 && lane < 16) {
        int w = wsum[lane], iw = w;
#pragma unroll
        for (int off = 1; off < 16; off <<= 1) {
            int t = __shfl_up(iw, off);
            if (lane >= off) iw += t;
        }
        woff_s[lane] = iw - w;
    }
    __syncthreads();
    if (idx < N) rowptr[idx + 1] = csum[blockIdx.x] + woff_s[wid] + incl;
    if (blockIdx.x == 0 && tid == 0) rowptr[0] = 0;
}

// ---------- CSR build: scatter src ids into dst-sorted order ----------
__global__ void scatter_kernel(const int* __restrict__ ei, int E, int Etot,
                               const int* __restrict__ rowptr, int* __restrict__ fill,
                               int* __restrict__ ssrc) {
    int eid = blockIdx.x * 256 + threadIdx.x;
    if (eid >= Etot) return;
    int s, d;
    edge_sd(ei, E, eid, s, d);
    int pos = rowptr[d] + atomicAdd(&fill[d], 1);
    ssrc[pos] = s;
}

// ---------- fused softmax + aggregation: one wave per dst, 8 edges per iteration ----------
// Exp phase: lane = j*8 + hj computes w = exp(lrelu(a_src[s_j, hj] + a_dst[dst, hj]))
//   -> 64 distinct exps per iteration (8 edges x 8 heads), 8x less expf than per-edge loop.
// Feature phase: broadcast s_j (uniform readlane -> SGPR base, coalesced) and w via bpermute;
//   issue all 8 Hbf row loads back-to-back (8 loads in flight), then pure FMA unroll.
// No max subtraction (e is O(+-10), exp safe in fp32; matches softmax exactly up to rounding).
__global__ __launch_bounds__(256) void agg_kernel(const int* __restrict__ rowptr,
                                                  const int* __restrict__ ssrc,
                                                  const float* __restrict__ a_src,
                                                  const float* __restrict__ a_dst,
                                                  const unsigned short* __restrict__ Hbf,
                                                  float* __restrict__ outbuf, int N) {
    int wid = threadIdx.x >> 6;
    int dst = blockIdx.x * 4 + wid;
    if (dst >= N) return;
    int lane = threadIdx.x & 63;
    int j  = lane >> 3;      // edge slot 0..7 (exp phase)
    int hj = lane & 7;       // head (exp phase)
    int hf = lane >> 3;      // head owning this lane's feature pair (f/16)
    int f  = lane * 2;       // features f, f+1
    int start = rowptr[dst], end = rowptr[dst + 1];
    float adst = a_dst[dst * 8 + hj];

    float acc0 = 0.f, acc1 = 0.f, denl = 0.f;
    for (int base = start; base < end; base += 8) {
        int i = base + j;
        int s = (i < end) ? ssrc[i] : -1;
        float w = 0.f;
        if (s >= 0) w = __expf(lrelu(a_src[s * 8 + hj] + adst));
        denl += w;

        int   sA[8];
        float wA[8];
        unsigned uA[8];
#pragma unroll
        for (int j2 = 0; j2 < 8; j2++) {
            sA[j2] = __shfl(s, j2 * 8);          // uniform lane -> readlane (SGPR)
            wA[j2] = __shfl(w, j2 * 8 + hf);     // per-lane head -> bpermute
        }
#pragma unroll
        for (int j2 = 0; j2 < 8; j2++)
            uA[j2] = (sA[j2] >= 0) ? *(const unsigned*)(Hbf + (size_t)sA[j2] * 128 + f) : 0u;
#pragma unroll
        for (int j2 = 0; j2 < 8; j2++) {
            acc0 += wA[j2] * __uint_as_float(uA[j2] << 16);
            acc1 += wA[j2] * __uint_as_float(uA[j2] & 0xffff0000u);
        }
    }
    // reduce den over the 8 slots (stride-8 lanes share a head)
#pragma unroll
    for (int off = 8; off < 64; off <<= 1) denl += __shfl_xor(denl, off);
    // lane hf (slot 0, head hf) now holds den for head hf
    float den = __shfl(denl, hf);
    float inv = 1.f / (den + 1e-16f);
    *(float2*)(outbuf + (size_t)dst * 128 + f) = make_float2(acc0 * inv, acc1 * inv);
}

// ---------- batch-norm stats: two-stage deterministic reduction (NO atomics) ----------
template <int C>
__global__ __launch_bounds__(256) void stats_part_kernel(const float* __restrict__ X, int Nrows,
                                                         float* __restrict__ partial,
                                                         int rows_per_block) {
    constexpr int GSZ = 256 / C;
    __shared__ float ls[256], lq[256];
    int c = threadIdx.x % C;
    int g = threadIdx.x / C;
    long base = (long)blockIdx.x * rows_per_block;
    long endr = base + rows_per_block;
    if (endr > Nrows) endr = Nrows;
    float s = 0.f, q = 0.f;
    for (long r = base + g; r < endr; r += GSZ) {
        float v = X[r * C + c];
        s += v;
        q += v * v;
    }
    ls[threadIdx.x] = s;
    lq[threadIdx.x] = q;
    __syncthreads();
#pragma unroll
    for (int st = GSZ / 2; st > 0; st >>= 1) {
        if (g < st) {
            ls[threadIdx.x] += ls[threadIdx.x + st * C];
            lq[threadIdx.x] += lq[threadIdx.x + st * C];
        }
        __syncthreads();
    }
    if (g == 0) {
        partial[(size_t)blockIdx.x * (2 * C) + c] = ls[c];
        partial[(size_t)blockIdx.x * (2 * C) + C + c] = lq[c];
    }
}

template <int C>
__global__ void stats_final_kernel(const float* __restrict__ partial, int nblk, float invN,
                                   float* __restrict__ mu, float* __restrict__ rsig) {
    int c = threadIdx.x;
    if (c >= C) return;
    float s = 0.f, q = 0.f;
    for (int b = 0; b < nblk; b++) {
        s += partial[(size_t)b * (2 * C) + c];
        q += partial[(size_t)b * (2 * C) + C + c];
    }
    float m_ = s * invN;
    float v = q * invN - m_ * m_;
    mu[c] = m_;
    rsig[c] = rsqrtf(v + BN_EPS);
}

// ---------- BN + ELU elementwise (128 cols, float4) ----------
__global__ void bn_elu_kernel(const float* __restrict__ X,
                              const float* __restrict__ mu, const float* __restrict__ rsig,
                              const float* __restrict__ gamma, const float* __restrict__ beta,
                              float* __restrict__ Y, long total4) {
    long i = (long)blockIdx.x * 256 + threadIdx.x;
    if (i >= total4) return;
    int c4 = (int)(i & 31) * 4;
    float4 x = ((const float4*)X)[i];
    float r[4] = {x.x, x.y, x.z, x.w};
#pragma unroll
    for (int j = 0; j < 4; j++) {
        int c = c4 + j;
        float v = (r[j] - mu[c]) * rsig[c] * gamma[c] + beta[c];
        r[j] = v > 0.f ? v : expm1f(v);   // ELU
    }
    ((float4*)Y)[i] = make_float4(r[0], r[1], r[2], r[3]);
}

// ---------- mean over heads: [N,8,16] -> [N,16] ----------
__global__ void headmean_kernel(const float* __restrict__ X, float* __restrict__ out1, int N) {
    int idx = blockIdx.x * 256 + threadIdx.x;   // n*4 + c4
    if (idx >= N * 4) return;
    int n = idx >> 2, c4 = (idx & 3) * 4;
    float4 acc = make_float4(0.f, 0.f, 0.f, 0.f);
#pragma unroll
    for (int h = 0; h < 8; h++) {
        float4 v = *(const float4*)(X + (size_t)n * 128 + h * 16 + c4);
        acc.x += v.x; acc.y += v.y; acc.z += v.z; acc.w += v.w;
    }
    acc.x *= 0.125f; acc.y *= 0.125f; acc.z *= 0.125f; acc.w *= 0.125f;
    *(float4*)(out1 + (size_t)n * 16 + c4) = acc;
}

// ---------- final: BN(16) + logits = v @ Wc + bc ----------
__global__ void final_kernel(const float* __restrict__ out1,
                             const float* __restrict__ mu, const float* __restrict__ rsig,
                             const float* __restrict__ gamma, const float* __restrict__ beta,
                             const float* __restrict__ Wc, const float* __restrict__ bc,
                             float* __restrict__ out, int N) {
    int n = blockIdx.x * 256 + threadIdx.x;
    if (n >= N) return;
    float l0 = bc[0], l1 = bc[1];
#pragma unroll
    for (int c = 0; c < 16; c++) {
        float v = (out1[(size_t)n * 16 + c] - mu[c]) * rsig[c] * gamma[c] + beta[c];
        l0 += v * Wc[c * 2 + 0];
        l1 += v * Wc[c * 2 + 1];
    }
    out[(size_t)n * 2 + 0] = l0;
    out[(size_t)n * 2 + 1] = l1;
}

// ---------- launcher ----------
extern "C" void kernel_launch(void* const* d_in, const int* in_sizes, int n_in,
                              void* d_out, int out_size, void* d_ws, size_t ws_size,
                              hipStream_t stream) {
    const float* x   = (const float*)d_in[0];
    const int*   ei  = (const int*)d_in[1];
    const float* W0  = (const float*)d_in[2];
    const float* as0 = (const float*)d_in[3];
    const float* ad0 = (const float*)d_in[4];
    // d_in[5] = b0: cancelled exactly by the following batch-norm's mean subtraction
    const float* g0  = (const float*)d_in[6];
    const float* be0 = (const float*)d_in[7];
    const float* W1  = (const float*)d_in[8];
    const float* as1 = (const float*)d_in[9];
    const float* ad1 = (const float*)d_in[10];
    // d_in[11] = b1: cancelled by BN as well
    const float* g1  = (const float*)d_in[12];
    const float* be1 = (const float*)d_in[13];
    const float* Wc  = (const float*)d_in[14];
    const float* bc  = (const float*)d_in[15];
    float* out = (float*)d_out;

    int N = in_sizes[0] / 128;
    int E = in_sizes[1] / 2;
    int Etot = E + N;

    // workspace layout
    char* ws = (char*)d_ws;
    size_t off = 0;
    auto walloc = [&](size_t bytes) -> void* {
        void* p = ws + off;
        off += (bytes + 255) & ~(size_t)255;
        return p;
    };
    float*          A       = (float*)walloc((size_t)N * 128 * 4);
    float*          B       = (float*)walloc((size_t)N * 128 * 4);
    unsigned short* Hbf     = (unsigned short*)walloc((size_t)N * 128 * 2);
    float*          a_src   = (float*)walloc((size_t)N * 8 * 4);
    float*          a_dst   = (float*)walloc((size_t)N * 8 * 4);
    float*          out1    = (float*)walloc((size_t)N * 16 * 4);
    int*            counts  = (int*)walloc((size_t)N * 4);
    int*            fill    = (int*)walloc((size_t)N * 4);
    int*            rowptr  = (int*)walloc((size_t)(N + 1) * 4);
    int*            csum    = (int*)walloc(64 * 4);
    int*            ssrc    = (int*)walloc((size_t)Etot * 4);
    float*          partial = (float*)walloc((size_t)256 * 256 * 4);   // [256 blocks][2*128]
    float*          stats   = (float*)walloc(2 * 128 * 4);
    float* mu = stats, * rsig = stats + 128;

    dim3 b256(256);
    int gN64    = (N + 63) / 64;
    int gNH     = (N * 8 + 255) / 256;
    int gE      = (Etot + 255) / 256;
    int gAgg    = (N + 3) / 4;
    int gElem4  = (int)(((long)N * 32 + 255) / 256);
    int nchunk  = (N + 1023) / 1024;
    const int SBLK = 256;
    int rpb = (N + SBLK - 1) / SBLK;

    // ---- CSR build (once; same graph for both layers) ----
    hipMemsetAsync(counts, 0, (size_t)N * 4, stream);
    hipMemsetAsync(fill, 0, (size_t)N * 4, stream);
    hist_kernel<<<gE, b256, 0, stream>>>(ei, E, Etot, counts);
    chunksum_kernel<<<nchunk, b256, 0, stream>>>(counts, csum, N);
    chunkscan_kernel<<<1, 64, 0, stream>>>(csum, nchunk);
    scanfinal_kernel<<<nchunk, 1024, 0, stream>>>(counts, csum, rowptr, N);
    scatter_kernel<<<gE, b256, 0, stream>>>(ei, E, Etot, rowptr, fill, ssrc);

    // ---- layer 0 ----
    gemm128<<<gN64, b256, 0, stream>>>(x, W0, A, Hbf, N);             // A = h0 (+ bf16 shadow)
    att_kernel<<<gNH, b256, 0, stream>>>(A, as0, ad0, a_src, a_dst, N);
    agg_kernel<<<gAgg, b256, 0, stream>>>(rowptr, ssrc, a_src, a_dst, Hbf, B, N);  // B = agg0
    stats_part_kernel<128><<<SBLK, b256, 0, stream>>>(B, N, partial, rpb);
    stats_final_kernel<128><<<1, 128, 0, stream>>>(partial, SBLK, 1.0f / N, mu, rsig);
    bn_elu_kernel<<<gElem4, b256, 0, stream>>>(B, mu, rsig, g0, be0, A, (long)N * 32); // A = h1_in

    // ---- layer 1 ----
    gemm128<<<gN64, b256, 0, stream>>>(A, W1, B, Hbf, N);             // B = h1 (+ bf16 shadow)
    att_kernel<<<gNH, b256, 0, stream>>>(B, as1, ad1, a_src, a_dst, N);
    agg_kernel<<<gAgg, b256, 0, stream>>>(rowptr, ssrc, a_src, a_dst, Hbf, A, N);  // A = agg1
    headmean_kernel<<<(N * 4 + 255) / 256, b256, 0, stream>>>(A, out1, N);
    stats_part_kernel<16><<<SBLK, b256, 0, stream>>>(out1, N, partial, rpb);
    stats_final_kernel<16><<<1, 16, 0, stream>>>(partial, SBLK, 1.0f / N, mu, rsig);
    final_kernel<<<(N + 255) / 256, b256, 0, stream>>>(out1, mu, rsig, g1, be1, Wc, bc, out, N);
}

// Round 6
// 357.688 us; speedup vs baseline: 12.7340x; 1.5218x over previous
//
#include <hip/hip_runtime.h>
#include <math.h>

#define NEG_SLOPE 0.2f
#define BN_EPS 1e-5f

// ---------- helpers ----------

__device__ __forceinline__ void edge_sd(const int* __restrict__ ei, int E, int eid, int& s, int& d) {
    if (eid < E) { s = ei[eid]; d = ei[E + eid]; }
    else         { s = d = eid - E; }   // self-loops appended after the E real edges
}

__device__ __forceinline__ float lrelu(float v) { return v > 0.f ? v : NEG_SLOPE * v; }

// round-to-nearest-even fp32 -> bf16 bits
__device__ __forceinline__ unsigned short f2bf(float f) {
    unsigned u = __float_as_uint(f);
    u += 0x7fffu + ((u >> 16) & 1u);
    return (unsigned short)(u >> 16);
}

// ---------- GEMM: Y[N,128] = act(X)[N,128] @ W[128,128]; also writes bf16 shadow ----------
// If bnmu != nullptr, applies BN+ELU to X elements while staging into LDS
// (fuses the inter-layer BN/ELU; X tile fully read before Y written -> in-place safe).
__global__ __launch_bounds__(256) void gemm128(const float* __restrict__ X,
                                               const float* __restrict__ W,
                                               float* __restrict__ Y,
                                               unsigned short* __restrict__ Ybf,
                                               const float* __restrict__ bnmu,
                                               const float* __restrict__ bnrs,
                                               const float* __restrict__ gamma,
                                               const float* __restrict__ beta,
                                               int Nrows) {
    __shared__ float xs[64 * 128];
    int bm = blockIdx.x * 64;
    int tid = threadIdx.x;

    const float4* Xv = (const float4*)(X + (size_t)bm * 128);
    float4* xsv = (float4*)xs;
    if (bnmu == nullptr) {
        for (int i = tid; i < 64 * 32; i += 256) {
            int row = i >> 5;
            xsv[i] = (bm + row < Nrows) ? Xv[i] : make_float4(0.f, 0.f, 0.f, 0.f);
        }
    } else {
        for (int i = tid; i < 64 * 32; i += 256) {
            int row = i >> 5;
            int cb = (i & 31) * 4;
            float4 v = (bm + row < Nrows) ? Xv[i] : make_float4(0.f, 0.f, 0.f, 0.f);
            float4 m4 = *(const float4*)(bnmu + cb);
            float4 r4 = *(const float4*)(bnrs + cb);
            float4 g4 = *(const float4*)(gamma + cb);
            float4 b4 = *(const float4*)(beta + cb);
            v.x = (v.x - m4.x) * r4.x * g4.x + b4.x;
            v.y = (v.y - m4.y) * r4.y * g4.y + b4.y;
            v.z = (v.z - m4.z) * r4.z * g4.z + b4.z;
            v.w = (v.w - m4.w) * r4.w * g4.w + b4.w;
            v.x = v.x > 0.f ? v.x : expm1f(v.x);
            v.y = v.y > 0.f ? v.y : expm1f(v.y);
            v.z = v.z > 0.f ? v.z : expm1f(v.z);
            v.w = v.w > 0.f ? v.w : expm1f(v.w);
            xsv[i] = v;
        }
    }
    __syncthreads();

    int cq = tid & 31;   // column quad: cols cq*4..cq*4+3
    int rg = tid >> 5;   // row group: rows rg*8..rg*8+7

    float acc[8][4];
#pragma unroll
    for (int r = 0; r < 8; r++)
#pragma unroll
        for (int j = 0; j < 4; j++) acc[r][j] = 0.f;

    const float* xbase = xs + (rg * 8) * 128;
#pragma unroll 4
    for (int k = 0; k < 128; k++) {
        float4 w4 = *(const float4*)(W + k * 128 + cq * 4);
#pragma unroll
        for (int r = 0; r < 8; r++) {
            float xv = xbase[r * 128 + k];
            acc[r][0] += xv * w4.x;
            acc[r][1] += xv * w4.y;
            acc[r][2] += xv * w4.z;
            acc[r][3] += xv * w4.w;
        }
    }
#pragma unroll
    for (int r = 0; r < 8; r++) {
        int row = bm + rg * 8 + r;
        if (row < Nrows) {
            *(float4*)(Y + (size_t)row * 128 + cq * 4) =
                make_float4(acc[r][0], acc[r][1], acc[r][2], acc[r][3]);
            ushort4 pk;
            pk.x = f2bf(acc[r][0]);
            pk.y = f2bf(acc[r][1]);
            pk.z = f2bf(acc[r][2]);
            pk.w = f2bf(acc[r][3]);
            *(ushort4*)(Ybf + (size_t)row * 128 + cq * 4) = pk;
        }
    }
}

// ---------- attention logits per node: a_src[n,h], a_dst[n,h] ----------
__global__ void att_kernel(const float* __restrict__ Hm,
                           const float* __restrict__ att_s,
                           const float* __restrict__ att_d,
                           float* __restrict__ a_src, float* __restrict__ a_dst, int N) {
    int idx = blockIdx.x * 256 + threadIdx.x;   // n*8 + h
    if (idx >= N * 8) return;
    int n = idx >> 3, h = idx & 7;
    const float* hp = Hm + (size_t)n * 128 + h * 16;
    float ss = 0.f, sd = 0.f;
#pragma unroll
    for (int c = 0; c < 16; c++) {
        float v = hp[c];
        ss += v * att_s[h * 16 + c];
        sd += v * att_d[h * 16 + c];
    }
    a_src[idx] = ss;
    a_dst[idx] = sd;
}

// ---------- CSR build: histogram of dst + within-bucket rank (atomic return value) ----------
__global__ void hist_kernel(const int* __restrict__ ei, int E, int Etot,
                            int* __restrict__ counts, int* __restrict__ rank) {
    int eid = blockIdx.x * 256 + threadIdx.x;
    if (eid >= Etot) return;
    int s, d;
    edge_sd(ei, E, eid, s, d);
    rank[eid] = atomicAdd(&counts[d], 1);
}

// ---------- CSR build: parallel 3-stage exclusive scan ----------
__global__ __launch_bounds__(256) void chunksum_kernel(const int* __restrict__ counts,
                                                       int* __restrict__ csum, int N) {
    __shared__ int red[256];
    int base = blockIdx.x * 1024;
    int s = 0;
    for (int i = threadIdx.x; i < 1024; i += 256) {
        int idx = base + i;
        s += (idx < N) ? counts[idx] : 0;
    }
    red[threadIdx.x] = s;
    __syncthreads();
#pragma unroll
    for (int st = 128; st > 0; st >>= 1) {
        if (threadIdx.x < st) red[threadIdx.x] += red[threadIdx.x + st];
        __syncthreads();
    }
    if (threadIdx.x == 0) csum[blockIdx.x] = red[0];
}

__global__ void chunkscan_kernel(int* __restrict__ csum, int nchunk) {
    int lane = threadIdx.x;
    int v = (lane < nchunk) ? csum[lane] : 0;
    int incl = v;
#pragma unroll
    for (int off = 1; off < 64; off <<= 1) {
        int t = __shfl_up(incl, off);
        if (lane >= off) incl += t;
    }
    if (lane < nchunk) csum[lane] = incl - v;
}

__global__ __launch_bounds__(1024) void scanfinal_kernel(const int* __restrict__ counts,
                                                         const int* __restrict__ csum,
                                                         int* __restrict__ rowptr, int N) {
    __shared__ int wsum[16], woff_s[16];
    int tid = threadIdx.x, lane = tid & 63, wid = tid >> 6;
    int idx = blockIdx.x * 1024 + tid;
    int v = (idx < N) ? counts[idx] : 0;
    int incl = v;
#pragma unroll
    for (int off = 1; off < 64; off <<= 1) {
        int t = __shfl_up(incl, off);
        if (lane >= off) incl += t;
    }
    if (lane == 63) wsum[wid] = incl;
    __syncthreads();
    if (wid == 0 && lane < 16) {
        int w = wsum[lane], iw = w;
#pragma unroll
        for (int off = 1; off < 16; off <<= 1) {
            int t = __shfl_up(iw, off);
            if (lane >= off) iw += t;
        }
        woff_s[lane] = iw - w;
    }
    __syncthreads();
    if (idx < N) rowptr[idx + 1] = csum[blockIdx.x] + woff_s[wid] + incl;
    if (blockIdx.x == 0 && tid == 0) rowptr[0] = 0;
}

// ---------- CSR build: scatter src ids (NO atomics; rank precomputed in hist) ----------
__global__ void scatter_kernel(const int* __restrict__ ei, int E, int Etot,
                               const int* __restrict__ rowptr, const int* __restrict__ rank,
                               unsigned short* __restrict__ ssrc) {
    int eid = blockIdx.x * 256 + threadIdx.x;
    if (eid >= Etot) return;
    int s, d;
    edge_sd(ei, E, eid, s, d);
    ssrc[rowptr[d] + rank[eid]] = (unsigned short)s;
}

// ---------- fused softmax + aggregation: one wave per dst, 8 edges per iteration ----------
// MEAN=false: writes full [dst,128]. MEAN=true: head-mean fused -> writes [dst,16].
template <bool MEAN>
__global__ __launch_bounds__(256) void agg_kernel(const int* __restrict__ rowptr,
                                                  const unsigned short* __restrict__ ssrc,
                                                  const float* __restrict__ a_src,
                                                  const float* __restrict__ a_dst,
                                                  const unsigned short* __restrict__ Hbf,
                                                  float* __restrict__ outbuf, int N) {
    int wid = threadIdx.x >> 6;
    int dst = blockIdx.x * 4 + wid;
    if (dst >= N) return;
    int lane = threadIdx.x & 63;
    int j  = lane >> 3;      // edge slot 0..7 (exp phase)
    int hj = lane & 7;       // head (exp phase)
    int hf = lane >> 3;      // head owning this lane's feature pair (f/16)
    int f  = lane * 2;       // features f, f+1
    int start = rowptr[dst], end = rowptr[dst + 1];
    float adst = a_dst[dst * 8 + hj];

    float acc0 = 0.f, acc1 = 0.f, denl = 0.f;
    for (int base = start; base < end; base += 8) {
        int i = base + j;
        int s = (i < end) ? (int)ssrc[i] : -1;
        float w = 0.f;
        if (s >= 0) w = __expf(lrelu(a_src[s * 8 + hj] + adst));
        denl += w;

        int   sA[8];
        float wA[8];
        unsigned uA[8];
#pragma unroll
        for (int j2 = 0; j2 < 8; j2++) {
            sA[j2] = __shfl(s, j2 * 8);          // uniform lane -> readlane (SGPR)
            wA[j2] = __shfl(w, j2 * 8 + hf);     // per-lane head -> bpermute
        }
#pragma unroll
        for (int j2 = 0; j2 < 8; j2++)
            uA[j2] = (sA[j2] >= 0) ? *(const unsigned*)(Hbf + (size_t)sA[j2] * 128 + f) : 0u;
#pragma unroll
        for (int j2 = 0; j2 < 8; j2++) {
            acc0 += wA[j2] * __uint_as_float(uA[j2] << 16);
            acc1 += wA[j2] * __uint_as_float(uA[j2] & 0xffff0000u);
        }
    }
    // reduce den over the 8 slots (stride-8 lanes share a head)
#pragma unroll
    for (int off = 8; off < 64; off <<= 1) denl += __shfl_xor(denl, off);
    float den = __shfl(denl, hf);
    float inv = 1.f / (den + 1e-16f);
    if (!MEAN) {
        *(float2*)(outbuf + (size_t)dst * 128 + f) = make_float2(acc0 * inv, acc1 * inv);
    } else {
        // head-mean: reduce features c=f&15 across the 8 heads (lanes sharing lane%8)
        float r0 = acc0 * inv, r1 = acc1 * inv;
#pragma unroll
        for (int off = 8; off < 64; off <<= 1) {
            r0 += __shfl_xor(r0, off);
            r1 += __shfl_xor(r1, off);
        }
        if (lane < 8)
            *(float2*)(outbuf + (size_t)dst * 16 + lane * 2) =
                make_float2(r0 * 0.125f, r1 * 0.125f);
    }
}

// ---------- batch-norm stats: two-stage deterministic reduction (NO atomics) ----------
template <int C>
__global__ __launch_bounds__(256) void stats_part_kernel(const float* __restrict__ X, int Nrows,
                                                         float* __restrict__ partial,
                                                         int rows_per_block) {
    constexpr int GSZ = 256 / C;
    __shared__ float ls[256], lq[256];
    int c = threadIdx.x % C;
    int g = threadIdx.x / C;
    long base = (long)blockIdx.x * rows_per_block;
    long endr = base + rows_per_block;
    if (endr > Nrows) endr = Nrows;
    float s = 0.f, q = 0.f;
    for (long r = base + g; r < endr; r += GSZ) {
        float v = X[r * C + c];
        s += v;
        q += v * v;
    }
    ls[threadIdx.x] = s;
    lq[threadIdx.x] = q;
    __syncthreads();
#pragma unroll
    for (int st = GSZ / 2; st > 0; st >>= 1) {
        if (g < st) {
            ls[threadIdx.x] += ls[threadIdx.x + st * C];
            lq[threadIdx.x] += lq[threadIdx.x + st * C];
        }
        __syncthreads();
    }
    if (g == 0) {
        partial[(size_t)blockIdx.x * (2 * C) + c] = ls[c];
        partial[(size_t)blockIdx.x * (2 * C) + C + c] = lq[c];
    }
}

// Stage 2: PARALLEL reduction of nblk partials (1024 threads, G groups per column).
template <int C>
__global__ __launch_bounds__(1024) void stats_final_kernel(const float* __restrict__ partial,
                                                           int nblk, float invN,
                                                           float* __restrict__ mu,
                                                           float* __restrict__ rsig) {
    constexpr int G = 1024 / C;
    __shared__ float ls[1024], lq[1024];
    int c = threadIdx.x % C;
    int g = threadIdx.x / C;
    float s = 0.f, q = 0.f;
    for (int b = g; b < nblk; b += G) {
        s += partial[(size_t)b * (2 * C) + c];
        q += partial[(size_t)b * (2 * C) + C + c];
    }
    ls[threadIdx.x] = s;
    lq[threadIdx.x] = q;
    __syncthreads();
#pragma unroll
    for (int st = G / 2; st > 0; st >>= 1) {
        if (g < st) {
            ls[threadIdx.x] += ls[threadIdx.x + st * C];
            lq[threadIdx.x] += lq[threadIdx.x + st * C];
        }
        __syncthreads();
    }
    if (g == 0) {
        float m_ = ls[c] * invN;
        float v = lq[c] * invN - m_ * m_;
        mu[c] = m_;
        rsig[c] = rsqrtf(v + BN_EPS);
    }
}

// ---------- final: BN(16) + logits = v @ Wc + bc ----------
__global__ void final_kernel(const float* __restrict__ out1,
                             const float* __restrict__ mu, const float* __restrict__ rsig,
                             const float* __restrict__ gamma, const float* __restrict__ beta,
                             const float* __restrict__ Wc, const float* __restrict__ bc,
                             float* __restrict__ out, int N) {
    int n = blockIdx.x * 256 + threadIdx.x;
    if (n >= N) return;
    float l0 = bc[0], l1 = bc[1];
#pragma unroll
    for (int c = 0; c < 16; c++) {
        float v = (out1[(size_t)n * 16 + c] - mu[c]) * rsig[c] * gamma[c] + beta[c];
        l0 += v * Wc[c * 2 + 0];
        l1 += v * Wc[c * 2 + 1];
    }
    out[(size_t)n * 2 + 0] = l0;
    out[(size_t)n * 2 + 1] = l1;
}

// ---------- launcher ----------
extern "C" void kernel_launch(void* const* d_in, const int* in_sizes, int n_in,
                              void* d_out, int out_size, void* d_ws, size_t ws_size,
                              hipStream_t stream) {
    const float* x   = (const float*)d_in[0];
    const int*   ei  = (const int*)d_in[1];
    const float* W0  = (const float*)d_in[2];
    const float* as0 = (const float*)d_in[3];
    const float* ad0 = (const float*)d_in[4];
    // d_in[5] = b0: cancelled exactly by the following batch-norm's mean subtraction
    const float* g0  = (const float*)d_in[6];
    const float* be0 = (const float*)d_in[7];
    const float* W1  = (const float*)d_in[8];
    const float* as1 = (const float*)d_in[9];
    const float* ad1 = (const float*)d_in[10];
    // d_in[11] = b1: cancelled by BN as well
    const float* g1  = (const float*)d_in[12];
    const float* be1 = (const float*)d_in[13];
    const float* Wc  = (const float*)d_in[14];
    const float* bc  = (const float*)d_in[15];
    float* out = (float*)d_out;

    int N = in_sizes[0] / 128;
    int E = in_sizes[1] / 2;
    int Etot = E + N;

    // workspace layout
    char* ws = (char*)d_ws;
    size_t off = 0;
    auto walloc = [&](size_t bytes) -> void* {
        void* p = ws + off;
        off += (bytes + 255) & ~(size_t)255;
        return p;
    };
    float*          A       = (float*)walloc((size_t)N * 128 * 4);
    float*          B       = (float*)walloc((size_t)N * 128 * 4);
    unsigned short* Hbf     = (unsigned short*)walloc((size_t)N * 128 * 2);
    float*          a_src   = (float*)walloc((size_t)N * 8 * 4);
    float*          a_dst   = (float*)walloc((size_t)N * 8 * 4);
    float*          out1    = (float*)walloc((size_t)N * 16 * 4);
    int*            counts  = (int*)walloc((size_t)N * 4);
    int*            rowptr  = (int*)walloc((size_t)(N + 1) * 4);
    int*            rank    = (int*)walloc((size_t)Etot * 4);
    int*            csum    = (int*)walloc(64 * 4);
    unsigned short* ssrc    = (unsigned short*)walloc((size_t)Etot * 2);
    float*          partial = (float*)walloc((size_t)256 * 256 * 4);   // [256 blocks][2*128]
    float*          stats   = (float*)walloc(2 * 128 * 4);
    float* mu = stats, * rsig = stats + 128;

    dim3 b256(256);
    int gN64    = (N + 63) / 64;
    int gNH     = (N * 8 + 255) / 256;
    int gE      = (Etot + 255) / 256;
    int gAgg    = (N + 3) / 4;
    int nchunk  = (N + 1023) / 1024;
    const int SBLK = 256;
    int rpb = (N + SBLK - 1) / SBLK;

    // ---- CSR build (once; same graph for both layers) ----
    hipMemsetAsync(counts, 0, (size_t)N * 4, stream);
    hist_kernel<<<gE, b256, 0, stream>>>(ei, E, Etot, counts, rank);
    chunksum_kernel<<<nchunk, b256, 0, stream>>>(counts, csum, N);
    chunkscan_kernel<<<1, 64, 0, stream>>>(csum, nchunk);
    scanfinal_kernel<<<nchunk, 1024, 0, stream>>>(counts, csum, rowptr, N);
    scatter_kernel<<<gE, b256, 0, stream>>>(ei, E, Etot, rowptr, rank, ssrc);

    // ---- layer 0 ----
    gemm128<<<gN64, b256, 0, stream>>>(x, W0, A, Hbf, nullptr, nullptr, nullptr, nullptr, N);
    att_kernel<<<gNH, b256, 0, stream>>>(A, as0, ad0, a_src, a_dst, N);
    agg_kernel<false><<<gAgg, b256, 0, stream>>>(rowptr, ssrc, a_src, a_dst, Hbf, B, N); // B = agg0
    stats_part_kernel<128><<<SBLK, b256, 0, stream>>>(B, N, partial, rpb);
    stats_final_kernel<128><<<1, 1024, 0, stream>>>(partial, SBLK, 1.0f / N, mu, rsig);

    // ---- layer 1 (BN+ELU fused into gemm X-load; in-place B -> B) ----
    gemm128<<<gN64, b256, 0, stream>>>(B, W1, B, Hbf, mu, rsig, g0, be0, N);  // B = h1
    att_kernel<<<gNH, b256, 0, stream>>>(B, as1, ad1, a_src, a_dst, N);
    agg_kernel<true><<<gAgg, b256, 0, stream>>>(rowptr, ssrc, a_src, a_dst, Hbf, out1, N); // out1 = head-mean(agg1)
    stats_part_kernel<16><<<SBLK, b256, 0, stream>>>(out1, N, partial, rpb);
    stats_final_kernel<16><<<1, 1024, 0, stream>>>(partial, SBLK, 1.0f / N, mu, rsig);
    final_kernel<<<(N + 255) / 256, b256, 0, stream>>>(out1, mu, rsig, g1, be1, Wc, bc, out, N);
}